// Round 12
// baseline (263.884 us; speedup 1.0000x reference)
//
#include <hip/hip_runtime.h>
#include <math.h>

// ---- problem constants ----
#define BN    28800      // B*N tokens total
#define CC    256        // channels
#define HIDN  1024       // MLP hidden
#define WINS  512        // total windows (8 frames * 64)
#define WROWS (WINS*64)  // 32768 window rows
#define ATT_SCALE 0.1767766952966369f

typedef __bf16 bf16x8 __attribute__((ext_vector_type(8)));
typedef float  f32x4  __attribute__((ext_vector_type(4)));

__device__ __forceinline__ unsigned short f2bf(float f) {
    unsigned u = __float_as_uint(f);
    unsigned r = (u + 0x7FFFu + ((u >> 16) & 1u)) >> 16;
    return (unsigned short)r;
}
__device__ __forceinline__ float bf2f(unsigned short u) {
    return __uint_as_float((unsigned)u << 16);
}

// fast GELU (tanh form) with fast rcp; overflow-safe
__device__ __forceinline__ float gelu_f(float x) {
    float x3 = x * x * x;
    float e  = __expf(1.5957691216057308f * (x + 0.044715f * x3));  // exp(2y)
    float th = 1.0f - 2.0f * __builtin_amdgcn_rcpf(e + 1.0f);
    return 0.5f * x * (1.0f + th);
}

__device__ __forceinline__ void gl_lds16(const void* g, void* l) {
    __builtin_amdgcn_global_load_lds(
        (const __attribute__((address_space(1))) void*)g,
        (__attribute__((address_space(3))) void*)l, 16, 0, 0);
}

// ---------------- LayerNorm (plain): one wave per token, bf16 out ----------------
__global__ void ln_kernel(const float* __restrict__ x, const float* __restrict__ w,
                          const float* __restrict__ b, unsigned short* __restrict__ out, int ntok) {
    int tok  = (int)((blockIdx.x * blockDim.x + threadIdx.x) >> 6);
    int lane = threadIdx.x & 63;
    if (tok >= ntok) return;
    float4 v = reinterpret_cast<const float4*>(x + (size_t)tok * CC)[lane];
    float s  = v.x + v.y + v.z + v.w;
    float s2 = v.x*v.x + v.y*v.y + v.z*v.z + v.w*v.w;
#pragma unroll
    for (int off = 32; off >= 1; off >>= 1) {
        s  += __shfl_xor(s, off);
        s2 += __shfl_xor(s2, off);
    }
    float mean = s * (1.0f / CC);
    float var  = s2 * (1.0f / CC) - mean * mean;
    float rs   = rsqrtf(var + 1e-5f);
    float4 wv = reinterpret_cast<const float4*>(w)[lane];
    float4 bv = reinterpret_cast<const float4*>(b)[lane];
    ushort4 o;
    o.x = f2bf((v.x - mean) * rs * wv.x + bv.x);
    o.y = f2bf((v.y - mean) * rs * wv.y + bv.y);
    o.z = f2bf((v.z - mean) * rs * wv.z + bv.z);
    o.w = f2bf((v.w - mean) * rs * wv.w + bv.w);
    reinterpret_cast<ushort4*>(out + (size_t)tok * CC)[lane] = o;
}

// ---------------- fused LayerNorm + window gather ----------------
__global__ void ln_gather(const float* __restrict__ x, const float* __restrict__ w,
                          const float* __restrict__ b, unsigned short* __restrict__ dst) {
    int row  = (int)((blockIdx.x * blockDim.x + threadIdx.x) >> 6);
    int lane = threadIdx.x & 63;
    if (row >= WROWS) return;
    int win = row >> 6, l = row & 63;
    int f   = win >> 6;
    int wih = (win >> 3) & 7, wiw = win & 7;
    int r = l >> 3, s = l & 7;
    int h = wih * 8 + r, wc = wiw * 8 + s;
    if (h >= 60 || wc >= 60) {
        ushort4 z = {0, 0, 0, 0};
        reinterpret_cast<ushort4*>(dst + (size_t)row * CC)[lane] = z;
        return;
    }
    int oh = (h + 4) % 60, ow = (wc + 4) % 60;
    size_t tok = (size_t)f * 3600 + (size_t)oh * 60 + ow;
    float4 v = reinterpret_cast<const float4*>(x + tok * CC)[lane];
    float sm  = v.x + v.y + v.z + v.w;
    float s2 = v.x*v.x + v.y*v.y + v.z*v.z + v.w*v.w;
#pragma unroll
    for (int off = 32; off >= 1; off >>= 1) {
        sm += __shfl_xor(sm, off);
        s2 += __shfl_xor(s2, off);
    }
    float mean = sm * (1.0f / CC);
    float var  = s2 * (1.0f / CC) - mean * mean;
    float rs   = rsqrtf(var + 1e-5f);
    float4 wv = reinterpret_cast<const float4*>(w)[lane];
    float4 bv = reinterpret_cast<const float4*>(b)[lane];
    ushort4 o;
    o.x = f2bf((v.x - mean) * rs * wv.x + bv.x);
    o.y = f2bf((v.y - mean) * rs * wv.y + bv.y);
    o.z = f2bf((v.z - mean) * rs * wv.z + bv.z);
    o.w = f2bf((v.w - mean) * rs * wv.w + bv.w);
    reinterpret_cast<ushort4*>(dst + (size_t)row * CC)[lane] = o;
}

// ---------------- bf16 MFMA GEMM: 512 threads, 8 waves (2m x 4n), 256xTN tile ----------
// M-block = 256 channels (full segment); per-wave 128 x (TN/4), acc[8][NW].
// 3-buffer LDS, stage 2 ahead, one barrier per K-step, counted vmcnt.
// FUSE: 0 = bf16 out [tok][strideO] (vseg segment stores V^T [ch][32768]);
//       1 = f32 residual out with inverse-window scatter (fout = xres + gamma*val);
//       2 = f32 plain residual out.
template <bool GELU, int FUSE, int TN>
__global__ __launch_bounds__(512, (TN == 128) ? 4 : 2) void gemm_wa(
        const unsigned short* __restrict__ Wt,   // [Mtot][K] bf16
        const unsigned short* __restrict__ Act,  // [Ntok][K] bf16
        const float* __restrict__ b0, const float* __restrict__ b1,
        const float* __restrict__ b2, const float* __restrict__ b3,
        unsigned short* __restrict__ o0, unsigned short* __restrict__ o1,
        unsigned short* __restrict__ o2, unsigned short* __restrict__ o3,
        int strideO, int vseg, int K, int Ntok,
        const float* __restrict__ xres, const float* __restrict__ gammap,
        float* __restrict__ fout) {
    constexpr int NW   = TN / 64;                 // token fragments per wave (2 or 4)
    constexpr int BP   = TN / 128;                // B staging passes (1 or 2)
    constexpr int BUFB = 16384 + TN * 64;         // bytes per stage buffer (A 16KB + B)
    constexpr int HALVES = TN / 128;
    constexpr int POOLB = (3 * BUFB > 65536) ? 3 * BUFB : 65536;   // Cs needs 64 KB
    __shared__ __align__(16) char pool[POOLB];
    unsigned short* Cs = (unsigned short*)pool;

    const int t = threadIdx.x;          // 0..511
    const int w = t >> 6;               // 0..7
    const int l = t & 63;
    // ---- bijective XCD swizzle: m fastest within an XCD ----
    const int Mb = gridDim.x;
    int lin = blockIdx.y * Mb + blockIdx.x;
    int T = Mb * gridDim.y;
    int q = T >> 3, rr = T & 7;
    int xcd = lin & 7, slot = lin >> 3;
    int wid = (xcd < rr) ? (xcd * (q + 1) + slot)
                         : (rr * (q + 1) + (xcd - rr) * q + slot);
    const int m0 = (wid % Mb) * 256;
    const int n0 = (wid / Mb) * TN;

    const int wr = w >> 2;              // 0..1: rows wr*128
    const int wc = w & 3;               // 0..3: tokens wc*(TN/4)
    const int r = l & 15, g = l >> 4;
    const int gp = (g ^ ((r >> 1) & 3)) * 8;

    f32x4 acc[8][NW];
#pragma unroll
    for (int i = 0; i < 8; ++i)
#pragma unroll
        for (int j = 0; j < NW; ++j) { acc[i][j][0]=0.f; acc[i][j][1]=0.f; acc[i][j][2]=0.f; acc[i][j][3]=0.f; }

#define STAGE(k0, buf)                                                             \
    do {                                                                           \
        _Pragma("unroll")                                                          \
        for (int p = 0; p < 2; ++p) {                                              \
            int c    = p * 512 + t;                                                \
            int rowa = c >> 2;                                                     \
            int gla  = (c & 3) ^ ((rowa >> 1) & 3);                                \
            gl_lds16(Wt + (size_t)(m0 + rowa) * K + (k0) + gla * 8,                \
                     pool + (buf) * BUFB + (p * 512 + w * 64) * 16);               \
        }                                                                          \
        _Pragma("unroll")                                                          \
        for (int p = 0; p < BP; ++p) {                                             \
            int c    = p * 512 + t;                                                \
            int rowb = c >> 2;                                                     \
            int glb  = (c & 3) ^ ((rowb >> 1) & 3);                                \
            gl_lds16(Act + (size_t)(n0 + rowb) * K + (k0) + glb * 8,               \
                     pool + (buf) * BUFB + 16384 + (p * 512 + w * 64) * 16);       \
        }                                                                          \
    } while (0)

    STAGE(0, 0);
    STAGE(32, 1);
    const char* cb0 = pool;
    const char* cb1 = pool + BUFB;
    const char* cb2 = pool + 2 * BUFB;
    int sbuf = 2;
    const int nt = K >> 5;
    for (int kt = 0; kt < nt; ++kt) {
        if (kt < nt - 1) {
            if (TN == 128) asm volatile("s_waitcnt vmcnt(3)" ::: "memory");
            else           asm volatile("s_waitcnt vmcnt(4)" ::: "memory");
        } else {
            asm volatile("s_waitcnt vmcnt(0)" ::: "memory");
        }
        __builtin_amdgcn_s_barrier();
        __builtin_amdgcn_sched_barrier(0);
        const unsigned short* cA = (const unsigned short*)cb0;
        const unsigned short* cB = (const unsigned short*)(cb0 + 16384);
        bf16x8 bw[NW];
#pragma unroll
        for (int n = 0; n < NW; ++n)
            bw[n] = *reinterpret_cast<const bf16x8*>(&cB[(wc * (NW * 16) + n * 16 + r) * 32 + gp]);
        __builtin_amdgcn_s_setprio(1);
#pragma unroll
        for (int m = 0; m < 8; ++m) {
            bf16x8 af = *reinterpret_cast<const bf16x8*>(&cA[(wr * 128 + m * 16 + r) * 32 + gp]);
#pragma unroll
            for (int n = 0; n < NW; ++n)
                acc[m][n] = __builtin_amdgcn_mfma_f32_16x16x32_bf16(af, bw[n], acc[m][n], 0, 0, 0);
        }
        __builtin_amdgcn_s_setprio(0);
        if (kt + 2 < nt) {
            STAGE((kt + 2) * 32, sbuf);
            sbuf = (sbuf == 2) ? 0 : sbuf + 1;
        }
        const char* tmp = cb0; cb0 = cb1; cb1 = cb2; cb2 = tmp;
    }
#undef STAGE

    // ---- epilogue ----
    const int seg = m0 >> 8;
    const float* bp = (seg == 0) ? b0 : (seg == 1) ? b1 : (seg == 2) ? b2 : b3;
    unsigned short* op = (seg == 0) ? o0 : (seg == 1) ? o1 : (seg == 2) ? o2 : o3;

    if (FUSE == 0 && seg == vseg) {
        // direct transposed store [ch][32768] (V^T for attention)
#pragma unroll
        for (int m = 0; m < 8; ++m) {
            const int ch0 = wr * 128 + m * 16 + g * 4;
            float4 b4 = *reinterpret_cast<const float4*>(bp + ch0);
            const float bb[4] = {b4.x, b4.y, b4.z, b4.w};
#pragma unroll
            for (int n = 0; n < NW; ++n) {
                const int tok = n0 + wc * (NW * 16) + n * 16 + r;
#pragma unroll
                for (int j = 0; j < 4; ++j)
                    op[(size_t)(ch0 + j) * 32768 + tok] = f2bf(acc[m][n][j] + bb[j]);
            }
        }
        return;
    }

    const float gsc = (FUSE != 0) ? gammap[0] : 0.f;
    const int u16 = t & 31, trow = t >> 5;
#pragma unroll
    for (int h = 0; h < HALVES; ++h) {
        __syncthreads();   // prior half's reads (or K-loop reads) done before Cs overwrite
        if (HALVES == 1 || (wc >> 1) == h) {
#pragma unroll
            for (int m = 0; m < 8; ++m) {
                const int ch0 = wr * 128 + m * 16 + g * 4;       // 0..255
                float4 b4 = *reinterpret_cast<const float4*>(bp + ch0);
                const float bb[4] = {b4.x, b4.y, b4.z, b4.w};
#pragma unroll
                for (int n = 0; n < NW; ++n) {
                    const int tokh = (wc * (NW * 16) + n * 16 + r) & 127;
                    float cv[4];
#pragma unroll
                    for (int j = 0; j < 4; ++j) {
                        cv[j] = acc[m][n][j] + bb[j];
                        if (GELU) cv[j] = gelu_f(cv[j]);
                    }
                    ushort4 pk;
                    pk.x = f2bf(cv[0]); pk.y = f2bf(cv[1]); pk.z = f2bf(cv[2]); pk.w = f2bf(cv[3]);
                    int gran = (ch0 >> 2) ^ ((tokh & 15) << 1);
                    reinterpret_cast<ushort4*>(Cs)[tokh * 64 + gran] = pk;
                }
            }
        }
        __syncthreads();
        // coalesced store: 32 lanes x 16B = 512 B contiguous per token row
#pragma unroll
        for (int it = 0; it < 8; ++it) {
            int rowh = it * 16 + trow;
            int wrow = n0 + h * 128 + rowh;
            if (wrow >= Ntok) continue;
            int up = u16 ^ (rowh & 15);
            uint4 v = reinterpret_cast<const uint4*>(Cs)[rowh * 32 + up];
            if (FUSE == 0) {
                *reinterpret_cast<uint4*>(op + (size_t)wrow * strideO + u16 * 8) = v;
            } else {
                int tok;
                if (FUSE == 1) {
                    int win = wrow >> 6, l2 = wrow & 63;
                    int f = win >> 6, wih = (win >> 3) & 7, wiw = win & 7;
                    int r2 = l2 >> 3, s2 = l2 & 7;
                    int hh = wih * 8 + r2, wcol = wiw * 8 + s2;
                    if (hh >= 60 || wcol >= 60) continue;     // padding rows dropped
                    int oh = hh + 4; if (oh >= 60) oh -= 60;
                    int ow = wcol + 4; if (ow >= 60) ow -= 60;
                    tok = f * 3600 + oh * 60 + ow;
                } else {
                    tok = wrow;
                }
                const unsigned short* pu = (const unsigned short*)&v;
                const float* xr = xres + (size_t)tok * CC + u16 * 8;
                float4 xa = *reinterpret_cast<const float4*>(xr);
                float4 xb = *reinterpret_cast<const float4*>(xr + 4);
                float4 oa, ob;
                oa.x = xa.x + gsc * bf2f(pu[0]);
                oa.y = xa.y + gsc * bf2f(pu[1]);
                oa.z = xa.z + gsc * bf2f(pu[2]);
                oa.w = xa.w + gsc * bf2f(pu[3]);
                ob.x = xb.x + gsc * bf2f(pu[4]);
                ob.y = xb.y + gsc * bf2f(pu[5]);
                ob.z = xb.z + gsc * bf2f(pu[6]);
                ob.w = xb.w + gsc * bf2f(pu[7]);
                float* fo = fout + (size_t)tok * CC + u16 * 8;
                *reinterpret_cast<float4*>(fo) = oa;
                *reinterpret_cast<float4*>(fo + 4) = ob;
            }
        }
    }
}

// ---------------- bias table expansion: biasx[2][8][64][64] ----------------
__global__ void expand_bias(const float* __restrict__ sa, const float* __restrict__ ca,
                            float* __restrict__ dst) {
    int e = (int)(blockIdx.x * blockDim.x + threadIdx.x);   // 0..32767
    const float* src = (e < 16384) ? sa : ca;
    int e2 = e & 16383;
    int h = e2 >> 12, ij = e2 & 4095, i = ij >> 6, j = ij & 63;
    int ri = i >> 3, si = i & 7, rj = j >> 3, sj = j & 7;
    dst[e] = src[((ri - rj + 7) * 15 + (si - sj + 7)) * 8 + h];
}

// ---------------- MFMA attention: one wave per (window, head) ----------------
__global__ __launch_bounds__(256) void attn_mfma(
        const unsigned short* __restrict__ Q,   // [32768][256] bf16
        const unsigned short* __restrict__ K,   // [32768][256] bf16
        const unsigned short* __restrict__ VT,  // [256][32768] bf16
        const float* __restrict__ biasx,        // [8][64][64] f32
        unsigned short* __restrict__ AO) {      // [32768][256] bf16
    __shared__ __align__(16) unsigned short Pl[4][64 * 64];
    const int t = threadIdx.x;
    const int w = t >> 6, l = t & 63;
    const int win = blockIdx.x >> 1;
    const int h   = (blockIdx.x & 1) * 4 + w;
    const int c = l & 15, g = l >> 4;
    const int wih = (win >> 3) & 7, wiw = win & 7;
    const size_t qkbase = (size_t)win * 64 * CC + (size_t)h * 32;

    bf16x8 ka[4], qb[4];
#pragma unroll
    for (int mj = 0; mj < 4; ++mj)
        ka[mj] = *reinterpret_cast<const bf16x8*>(K + qkbase + (size_t)(mj * 16 + c) * CC + g * 8);
#pragma unroll
    for (int ni = 0; ni < 4; ++ni)
        qb[ni] = *reinterpret_cast<const bf16x8*>(Q + qkbase + (size_t)(ni * 16 + c) * CC + g * 8);
    f32x4 s[4][4];
#pragma unroll
    for (int mj = 0; mj < 4; ++mj)
#pragma unroll
        for (int ni = 0; ni < 4; ++ni) { s[mj][ni][0]=0.f; s[mj][ni][1]=0.f; s[mj][ni][2]=0.f; s[mj][ni][3]=0.f; }
#pragma unroll
    for (int mj = 0; mj < 4; ++mj)
#pragma unroll
        for (int ni = 0; ni < 4; ++ni)
            s[mj][ni] = __builtin_amdgcn_mfma_f32_16x16x32_bf16(ka[mj], qb[ni], s[mj][ni], 0, 0, 0);

    const float* bx = biasx + h * 4096;
    const bool modd = (wiw == 7) && (g & 1);
#pragma unroll
    for (int mj = 0; mj < 4; ++mj) {
        const bool mmj = (wih == 7) && (mj >= 2);
#pragma unroll
        for (int ni = 0; ni < 4; ++ni) {
            float4 b4 = *reinterpret_cast<const float4*>(bx + (ni * 16 + c) * 64 + mj * 16 + g * 4);
            const float bb[4] = {b4.x, b4.y, b4.z, b4.w};
#pragma unroll
            for (int jj = 0; jj < 4; ++jj) {
                float v = s[mj][ni][jj] * ATT_SCALE + bb[jj];
                s[mj][ni][jj] = (mmj || modd) ? -1e30f : v;
            }
        }
    }

#pragma unroll
    for (int ni = 0; ni < 4; ++ni) {
        float mx = -1e30f;
#pragma unroll
        for (int mj = 0; mj < 4; ++mj)
#pragma unroll
            for (int jj = 0; jj < 4; ++jj) mx = fmaxf(mx, s[mj][ni][jj]);
        mx = fmaxf(mx, __shfl_xor(mx, 16));
        mx = fmaxf(mx, __shfl_xor(mx, 32));
        float sum = 0.f;
#pragma unroll
        for (int mj = 0; mj < 4; ++mj)
#pragma unroll
            for (int jj = 0; jj < 4; ++jj) {
                float p = __expf(s[mj][ni][jj] - mx);
                s[mj][ni][jj] = p;
                sum += p;
            }
        sum += __shfl_xor(sum, 16);
        sum += __shfl_xor(sum, 32);
        float rinv = __builtin_amdgcn_rcpf(sum);
        const int i  = ni * 16 + c;
        const int ik = i & 7;
#pragma unroll
        for (int mj = 0; mj < 4; ++mj) {
            ushort4 pk;
            pk.x = f2bf(s[mj][ni][0] * rinv);
            pk.y = f2bf(s[mj][ni][1] * rinv);
            pk.z = f2bf(s[mj][ni][2] * rinv);
            pk.w = f2bf(s[mj][ni][3] * rinv);
            int chunk = (mj * 2 + (g >> 1)) ^ ik;
            *reinterpret_cast<ushort4*>((char*)&Pl[w][0] + i * 128 + chunk * 16 + (g & 1) * 8) = pk;
        }
    }

    bf16x8 vb[2][2];
#pragma unroll
    for (int nd = 0; nd < 2; ++nd)
#pragma unroll
        for (int kt = 0; kt < 2; ++kt)
            vb[nd][kt] = *reinterpret_cast<const bf16x8*>(
                VT + (size_t)(h * 32 + nd * 16 + c) * 32768 + win * 64 + kt * 32 + g * 8);
    f32x4 o[4][2];
#pragma unroll
    for (int mi = 0; mi < 4; ++mi)
#pragma unroll
        for (int nd = 0; nd < 2; ++nd) { o[mi][nd][0]=0.f; o[mi][nd][1]=0.f; o[mi][nd][2]=0.f; o[mi][nd][3]=0.f; }
#pragma unroll
    for (int mi = 0; mi < 4; ++mi) {
        const int i  = mi * 16 + c;
        const int ik = i & 7;
#pragma unroll
        for (int kt = 0; kt < 2; ++kt) {
            int chunk = (kt * 4 + g) ^ ik;
            bf16x8 pa = *reinterpret_cast<const bf16x8*>((char*)&Pl[w][0] + i * 128 + chunk * 16);
#pragma unroll
            for (int nd = 0; nd < 2; ++nd)
                o[mi][nd] = __builtin_amdgcn_mfma_f32_16x16x32_bf16(pa, vb[nd][kt], o[mi][nd], 0, 0, 0);
        }
    }

    unsigned short* aop = AO + qkbase;
#pragma unroll
    for (int mi = 0; mi < 4; ++mi)
#pragma unroll
        for (int nd = 0; nd < 2; ++nd)
#pragma unroll
            for (int jj = 0; jj < 4; ++jj)
                aop[(size_t)(mi * 16 + g * 4 + jj) * CC + nd * 16 + c] = f2bf(o[mi][nd][jj]);
}

// ---------------- weight fp32 -> bf16 conversion ----------------
__global__ void cvt_all(const float* s0, const float* s1, const float* s2, const float* s3,
                        const float* s4, const float* s5, const float* s6, const float* s7,
                        const float* s8, const float* s9, unsigned short* __restrict__ dst) {
    const float* srcs[10] = {s0, s1, s2, s3, s4, s5, s6, s7, s8, s9};
    int blk = blockIdx.x;
    int wi = (blk < 512) ? (blk >> 6) : (blk < 768 ? 8 : 9);
    size_t start = (wi < 8) ? (size_t)wi * 65536 : (wi == 8 ? (size_t)524288 : (size_t)786432);
    size_t gidx = (size_t)blk * 1024 + (size_t)threadIdx.x * 4;
    float4 v = *reinterpret_cast<const float4*>(srcs[wi] + (gidx - start));
    ushort4 o;
    o.x = f2bf(v.x); o.y = f2bf(v.y); o.z = f2bf(v.z); o.w = f2bf(v.w);
    *reinterpret_cast<ushort4*>(dst + gidx) = o;
}

extern "C" void kernel_launch(void* const* d_in, const int* in_sizes, int n_in,
                              void* d_out, int out_size, void* d_ws, size_t ws_size,
                              hipStream_t stream) {
    const float* x    = (const float*)d_in[0];
    const float* ctx  = (const float*)d_in[1];
    const float* ln1w = (const float*)d_in[2];
    const float* ln1b = (const float*)d_in[3];
    const float* ln2w = (const float*)d_in[4];
    const float* ln2b = (const float*)d_in[5];
    const float* ln3w = (const float*)d_in[6];
    const float* ln3b = (const float*)d_in[7];
    const float* lncw = (const float*)d_in[8];
    const float* lncb = (const float*)d_in[9];
    const float* saqw = (const float*)d_in[10];
    const float* saqb = (const float*)d_in[11];
    const float* sakw = (const float*)d_in[12];
    const float* sakb = (const float*)d_in[13];
    const float* savw = (const float*)d_in[14];
    const float* savb = (const float*)d_in[15];
    const float* saow = (const float*)d_in[16];
    const float* saob = (const float*)d_in[17];
    const float* sabias = (const float*)d_in[18];
    const float* caqw = (const float*)d_in[19];
    const float* caqb = (const float*)d_in[20];
    const float* cakw = (const float*)d_in[21];
    const float* cakb = (const float*)d_in[22];
    const float* cavw = (const float*)d_in[23];
    const float* cavb = (const float*)d_in[24];
    const float* caow = (const float*)d_in[25];
    const float* caob = (const float*)d_in[26];
    const float* cabias = (const float*)d_in[27];
    const float* gamma1 = (const float*)d_in[28];
    const float* gamma2 = (const float*)d_in[29];
    const float* gammam = (const float*)d_in[30];
    const float* mw1 = (const float*)d_in[31];
    const float* mb1 = (const float*)d_in[32];
    const float* mw2 = (const float*)d_in[33];
    const float* mb2 = (const float*)d_in[34];

    float* ws = (float*)d_ws;
    unsigned short* LNbf = (unsigned short*)(ws);                 // 3,686,400 f
    unsigned short* Gq   = (unsigned short*)(ws + 3686400);       // 4,194,304 f
    unsigned short* Gkv  = (unsigned short*)(ws + 7880704);       // 4,194,304 f
    unsigned short* Qbf  = (unsigned short*)(ws + 12075008);      // 4,194,304 f
    unsigned short* Kbf  = (unsigned short*)(ws + 16269312);      // 4,194,304 f
    unsigned short* VTbf = (unsigned short*)(ws + 20463616);      // 4,194,304 f
    float* X1  = ws + 28852224;                                   // 7,372,800 f
    unsigned short* Wp = (unsigned short*)(ws + 36225024);        // 524,288 f
    float* biasx = ws + 36749312;                                 // 32,768 f
    unsigned short* AObf = Gq;                                    // alias (gathered act dead after proj)
    unsigned short* H1bf = Qbf;                                   // alias (Q/K/VT dead in MLP phase)

    // cvt layout (contiguous): saq|sak|sav | sao | caq | cak|cav | cao | m1 | m2
    unsigned short* w_saqkv = Wp;                                 // [768][256]
    unsigned short* w_sao   = Wp + 196608;                        // [256][256]
    unsigned short* w_caq   = Wp + 262144;                        // [256][256]
    unsigned short* w_cakv  = Wp + 327680;                        // [512][256]
    unsigned short* w_cao   = Wp + 458752;                        // [256][256]
    unsigned short* w_m1    = Wp + 524288;                        // [1024][256]
    unsigned short* w_m2    = Wp + 786432;                        // [256][1024]

    float* OUT = (float*)d_out;

    dim3 blk(256);
    dim3 blk512(512);
    dim3 gLN(BN / 4);
    dim3 gGather(WROWS / 4);
    dim3 gAttn(WINS * 2);

    cvt_all<<<dim3(1024), blk, 0, stream>>>(saqw, sakw, savw, saow, caqw, cakw, cavw, caow, mw1, mw2, Wp);
    expand_bias<<<dim3(128), blk, 0, stream>>>(sabias, cabias, biasx);

    // ---- self attention ----
    ln_gather<<<gGather, blk, 0, stream>>>(x, ln1w, ln1b, Gq);
    gemm_wa<false,0,256><<<dim3(3, 128), blk512, 0, stream>>>(w_saqkv, Gq, saqb, sakb, savb, savb,
                                                              Qbf, Kbf, VTbf, VTbf, CC, 2, CC, WROWS,
                                                              nullptr, nullptr, nullptr);
    attn_mfma<<<gAttn, blk, 0, stream>>>(Qbf, Kbf, VTbf, biasx, AObf);
    gemm_wa<false,1,128><<<dim3(1, 256), blk512, 0, stream>>>(w_sao, AObf, saob, saob, saob, saob,
                                                              Qbf, Qbf, Qbf, Qbf, CC, -1, CC, WROWS,
                                                              x, gamma1, X1);
    // ---- cross attention ----
    ln_gather<<<gGather, blk, 0, stream>>>(X1, ln2w, ln2b, Gq);
    ln_gather<<<gGather, blk, 0, stream>>>(ctx, lncw, lncb, Gkv);
    gemm_wa<false,0,128><<<dim3(1, 256), blk512, 0, stream>>>(w_caq, Gq, caqb, caqb, caqb, caqb,
                                                              Qbf, Qbf, Qbf, Qbf, CC, -1, CC, WROWS,
                                                              nullptr, nullptr, nullptr);
    gemm_wa<false,0,256><<<dim3(2, 128), blk512, 0, stream>>>(w_cakv, Gkv, cakb, cavb, cavb, cavb,
                                                              Kbf, VTbf, VTbf, VTbf, CC, 1, CC, WROWS,
                                                              nullptr, nullptr, nullptr);
    attn_mfma<<<gAttn, blk, 0, stream>>>(Qbf, Kbf, VTbf, biasx + 16384, AObf);
    gemm_wa<false,1,128><<<dim3(1, 256), blk512, 0, stream>>>(w_cao, AObf, caob, caob, caob, caob,
                                                              Qbf, Qbf, Qbf, Qbf, CC, -1, CC, WROWS,
                                                              X1, gamma2, X1);
    // ---- MLP ----
    ln_kernel<<<gLN, blk, 0, stream>>>(X1, ln3w, ln3b, LNbf, BN);
    gemm_wa<true,0,256><<<dim3(4, 113), blk512, 0, stream>>>(w_m1, LNbf, mb1, mb1 + 256, mb1 + 512, mb1 + 768,
                                                             H1bf, H1bf + 256, H1bf + 512, H1bf + 768,
                                                             HIDN, -1, CC, BN, nullptr, nullptr, nullptr);
    gemm_wa<false,2,128><<<dim3(1, 225), blk512, 0, stream>>>(w_m2, H1bf, mb2, mb2, mb2, mb2,
                                                             Qbf, Qbf, Qbf, Qbf, CC, -1, HIDN, BN,
                                                             X1, gammam, OUT);
}

// Round 13
// 225.146 us; speedup vs baseline: 1.1721x; 1.1721x over previous
//
#include <hip/hip_runtime.h>
#include <math.h>

// ---- problem constants ----
#define BN    28800      // B*N tokens total
#define CC    256        // channels
#define HIDN  1024       // MLP hidden
#define WINS  512        // total windows (8 frames * 64)
#define WROWS (WINS*64)  // 32768 window rows
#define ATT_SCALE 0.1767766952966369f

typedef __bf16 bf16x8 __attribute__((ext_vector_type(8)));
typedef float  f32x4  __attribute__((ext_vector_type(4)));

__device__ __forceinline__ unsigned short f2bf(float f) {
    unsigned u = __float_as_uint(f);
    unsigned r = (u + 0x7FFFu + ((u >> 16) & 1u)) >> 16;
    return (unsigned short)r;
}
__device__ __forceinline__ float bf2f(unsigned short u) {
    return __uint_as_float((unsigned)u << 16);
}

// fast GELU (tanh form) with fast rcp; overflow-safe
__device__ __forceinline__ float gelu_f(float x) {
    float x3 = x * x * x;
    float e  = __expf(1.5957691216057308f * (x + 0.044715f * x3));  // exp(2y)
    float th = 1.0f - 2.0f * __builtin_amdgcn_rcpf(e + 1.0f);
    return 0.5f * x * (1.0f + th);
}

__device__ __forceinline__ void gl_lds16(const void* g, void* l) {
    __builtin_amdgcn_global_load_lds(
        (const __attribute__((address_space(1))) void*)g,
        (__attribute__((address_space(3))) void*)l, 16, 0, 0);
}

// ---------------- fused LayerNorm + window gather ----------------
__global__ void ln_gather(const float* __restrict__ x, const float* __restrict__ w,
                          const float* __restrict__ b, unsigned short* __restrict__ dst) {
    int row  = (int)((blockIdx.x * blockDim.x + threadIdx.x) >> 6);
    int lane = threadIdx.x & 63;
    if (row >= WROWS) return;
    int win = row >> 6, l = row & 63;
    int f   = win >> 6;
    int wih = (win >> 3) & 7, wiw = win & 7;
    int r = l >> 3, s = l & 7;
    int h = wih * 8 + r, wc = wiw * 8 + s;
    if (h >= 60 || wc >= 60) {
        ushort4 z = {0, 0, 0, 0};
        reinterpret_cast<ushort4*>(dst + (size_t)row * CC)[lane] = z;
        return;
    }
    int oh = (h + 4) % 60, ow = (wc + 4) % 60;
    size_t tok = (size_t)f * 3600 + (size_t)oh * 60 + ow;
    float4 v = reinterpret_cast<const float4*>(x + tok * CC)[lane];
    float sm  = v.x + v.y + v.z + v.w;
    float s2 = v.x*v.x + v.y*v.y + v.z*v.z + v.w*v.w;
#pragma unroll
    for (int off = 32; off >= 1; off >>= 1) {
        sm += __shfl_xor(sm, off);
        s2 += __shfl_xor(s2, off);
    }
    float mean = sm * (1.0f / CC);
    float var  = s2 * (1.0f / CC) - mean * mean;
    float rs   = rsqrtf(var + 1e-5f);
    float4 wv = reinterpret_cast<const float4*>(w)[lane];
    float4 bv = reinterpret_cast<const float4*>(b)[lane];
    ushort4 o;
    o.x = f2bf((v.x - mean) * rs * wv.x + bv.x);
    o.y = f2bf((v.y - mean) * rs * wv.y + bv.y);
    o.z = f2bf((v.z - mean) * rs * wv.z + bv.z);
    o.w = f2bf((v.w - mean) * rs * wv.w + bv.w);
    reinterpret_cast<ushort4*>(dst + (size_t)row * CC)[lane] = o;
}

// ---------------- bf16 MFMA GEMM: 512 threads, 8 waves (2x4), 128xTN tile ----------------
// (round-11 verbatim) 3-buffer LDS, stage 2 ahead, one barrier per K-step.
// FUSE: 0 = bf16 out [tok][strideO] (vseg segment stores V^T [ch][32768]);
//       2 = f32 plain residual out.
template <bool GELU, int FUSE, int TN>
__global__ __launch_bounds__(512, 4) void gemm_wa(
        const unsigned short* __restrict__ Wt,   // [Mtot][K] bf16
        const unsigned short* __restrict__ Act,  // [Ntok][K] bf16
        const float* __restrict__ b0, const float* __restrict__ b1,
        const float* __restrict__ b2, const float* __restrict__ b3,
        unsigned short* __restrict__ o0, unsigned short* __restrict__ o1,
        unsigned short* __restrict__ o2, unsigned short* __restrict__ o3,
        int strideO, int vseg, int K, int Ntok,
        const float* __restrict__ xres, const float* __restrict__ gammap,
        float* __restrict__ fout) {
    constexpr int NW   = TN / 64;               // 16-col fragments per wave (2 or 4)
    constexpr int BP   = TN / 128;              // B staging passes per step
    constexpr int BUFB = 8192 + TN * 64;        // bytes per stage buffer (A + B)
    constexpr int POOLB = (3 * BUFB > TN * 256) ? 3 * BUFB : TN * 256;
    __shared__ __align__(16) char pool[POOLB];
    unsigned short* Cs = (unsigned short*)pool;

    const int t = threadIdx.x;          // 0..511
    const int w = t >> 6;               // 0..7
    const int l = t & 63;
    // ---- bijective XCD swizzle: m fastest within an XCD ----
    const int Mb = gridDim.x;
    int lin = blockIdx.y * Mb + blockIdx.x;
    int T = Mb * gridDim.y;
    int q = T >> 3, rr = T & 7;
    int xcd = lin & 7, slot = lin >> 3;
    int wid = (xcd < rr) ? (xcd * (q + 1) + slot)
                         : (rr * (q + 1) + (xcd - rr) * q + slot);
    const int m0 = (wid % Mb) * 128;
    const int n0 = (wid / Mb) * TN;

    const int wr = w >> 2, wc = w & 3;  // wave tile: rows wr*64, cols wc*(NW*16)
    const int r = l & 15, g = l >> 4;
    const int gp = (g ^ ((r >> 1) & 3)) * 8;
    const int srow = t >> 2;
    const int sgl  = (t & 3) ^ ((srow >> 1) & 3);

    f32x4 acc[4][NW];
#pragma unroll
    for (int i = 0; i < 4; ++i)
#pragma unroll
        for (int j = 0; j < NW; ++j) { acc[i][j][0]=0.f; acc[i][j][1]=0.f; acc[i][j][2]=0.f; acc[i][j][3]=0.f; }

#define STAGE(k0, buf)                                                             \
    do {                                                                           \
        gl_lds16(Wt + (size_t)(m0 + srow) * K + (k0) + sgl * 8,                    \
                 pool + (buf) * BUFB + w * 1024);                                  \
        _Pragma("unroll")                                                          \
        for (int p = 0; p < BP; ++p) {                                             \
            int c    = p * 512 + t;                                                \
            int rowb = c >> 2;                                                     \
            int glb  = (c & 3) ^ ((rowb >> 1) & 3);                                \
            gl_lds16(Act + (size_t)(n0 + rowb) * K + (k0) + glb * 8,               \
                     pool + (buf) * BUFB + 8192 + p * 8192 + w * 1024);            \
        }                                                                          \
    } while (0)

    STAGE(0, 0);
    STAGE(32, 1);
    const char* cb0 = pool;
    const char* cb1 = pool + BUFB;
    const char* cb2 = pool + 2 * BUFB;
    int sbuf = 2;
    const int nt = K >> 5;
    for (int kt = 0; kt < nt; ++kt) {
        if (kt < nt - 1) {
            if (TN == 128) asm volatile("s_waitcnt vmcnt(2)" ::: "memory");
            else           asm volatile("s_waitcnt vmcnt(3)" ::: "memory");
        } else {
            asm volatile("s_waitcnt vmcnt(0)" ::: "memory");
        }
        __builtin_amdgcn_s_barrier();
        __builtin_amdgcn_sched_barrier(0);
        const unsigned short* cA = (const unsigned short*)cb0;
        const unsigned short* cB = (const unsigned short*)(cb0 + 8192);
        bf16x8 bw[NW];
#pragma unroll
        for (int n = 0; n < NW; ++n)
            bw[n] = *reinterpret_cast<const bf16x8*>(&cB[(wc * (NW * 16) + n * 16 + r) * 32 + gp]);
        __builtin_amdgcn_s_setprio(1);
#pragma unroll
        for (int m = 0; m < 4; ++m) {
            bf16x8 af = *reinterpret_cast<const bf16x8*>(&cA[(wr * 64 + m * 16 + r) * 32 + gp]);
#pragma unroll
            for (int n = 0; n < NW; ++n)
                acc[m][n] = __builtin_amdgcn_mfma_f32_16x16x32_bf16(af, bw[n], acc[m][n], 0, 0, 0);
        }
        __builtin_amdgcn_s_setprio(0);
        if (kt + 2 < nt) {
            STAGE((kt + 2) * 32, sbuf);
            sbuf = (sbuf == 2) ? 0 : sbuf + 1;
        }
        const char* tmp = cb0; cb0 = cb1; cb1 = cb2; cb2 = tmp;
    }
#undef STAGE

    // ---- epilogue ----
    const int seg = m0 >> 8;
    const float* bp = (seg == 0) ? b0 : (seg == 1) ? b1 : (seg == 2) ? b2 : b3;
    unsigned short* op = (seg == 0) ? o0 : (seg == 1) ? o1 : (seg == 2) ? o2 : o3;
    const int chseg = m0 & 255;

    if (FUSE == 0 && seg == vseg) {
        // direct transposed store [ch][32768] (V^T for attention)
#pragma unroll
        for (int m = 0; m < 4; ++m) {
            const int ch0 = chseg + wr * 64 + m * 16 + g * 4;
            float4 b4 = *reinterpret_cast<const float4*>(bp + ch0);
            const float bb[4] = {b4.x, b4.y, b4.z, b4.w};
#pragma unroll
            for (int n = 0; n < NW; ++n) {
                const int tok = n0 + wc * (NW * 16) + n * 16 + r;
#pragma unroll
                for (int j = 0; j < 4; ++j)
                    op[(size_t)(ch0 + j) * 32768 + tok] = f2bf(acc[m][n][j] + bb[j]);
            }
        }
        return;
    }

    __syncthreads();   // all waves done with final ds_reads before Cs overwrite
#pragma unroll
    for (int m = 0; m < 4; ++m) {
        const int ch0 = wr * 64 + m * 16 + g * 4;       // local 0..127
        float4 b4 = *reinterpret_cast<const float4*>(bp + chseg + ch0);
        const float bb[4] = {b4.x, b4.y, b4.z, b4.w};
#pragma unroll
        for (int n = 0; n < NW; ++n) {
            const int tok_l = wc * (NW * 16) + n * 16 + r;   // local 0..TN-1
            float cv[4];
#pragma unroll
            for (int j = 0; j < 4; ++j) {
                cv[j] = acc[m][n][j] + bb[j];
                if (GELU) cv[j] = gelu_f(cv[j]);
            }
            ushort4 pk;
            pk.x = f2bf(cv[0]); pk.y = f2bf(cv[1]); pk.z = f2bf(cv[2]); pk.w = f2bf(cv[3]);
            int gran = (ch0 >> 2) ^ ((tok_l & 15) << 1);
            reinterpret_cast<ushort4*>(Cs)[tok_l * 32 + gran] = pk;
        }
    }
    __syncthreads();
    const int u = t & 15, trow = t >> 4;   // trow 0..31
    if (FUSE == 0) {
#pragma unroll
        for (int it = 0; it < TN / 32; ++it) {
            int tok_l = it * 32 + trow;
            if (n0 + tok_l >= Ntok) continue;
            int up = u ^ (tok_l & 15);
            uint4 v = reinterpret_cast<const uint4*>(Cs)[tok_l * 16 + up];
            *reinterpret_cast<uint4*>(op + (size_t)(n0 + tok_l) * strideO + chseg + u * 8) = v;
        }
    } else {
        const float gsc = gammap[0];
#pragma unroll
        for (int it = 0; it < TN / 32; ++it) {
            int tok_l = it * 32 + trow;
            int wrow = n0 + tok_l;
            if (wrow >= Ntok) continue;
            int tok = wrow;
            int up = u ^ (tok_l & 15);
            uint4 v = reinterpret_cast<const uint4*>(Cs)[tok_l * 16 + up];
            const unsigned short* pu = (const unsigned short*)&v;
            const float* xr = xres + (size_t)tok * CC + chseg + u * 8;
            float4 xa = *reinterpret_cast<const float4*>(xr);
            float4 xb = *reinterpret_cast<const float4*>(xr + 4);
            float4 oa, ob;
            oa.x = xa.x + gsc * bf2f(pu[0]);
            oa.y = xa.y + gsc * bf2f(pu[1]);
            oa.z = xa.z + gsc * bf2f(pu[2]);
            oa.w = xa.w + gsc * bf2f(pu[3]);
            ob.x = xb.x + gsc * bf2f(pu[4]);
            ob.y = xb.y + gsc * bf2f(pu[5]);
            ob.z = xb.z + gsc * bf2f(pu[6]);
            ob.w = xb.w + gsc * bf2f(pu[7]);
            float* fo = fout + (size_t)tok * CC + chseg + u * 8;
            *reinterpret_cast<float4*>(fo) = oa;
            *reinterpret_cast<float4*>(fo + 4) = ob;
        }
    }
}

// ---------------- o-proj GEMM with fused residual + LayerNorm output ----------------
// M = 256 (full channels, one m-block), TN = 128 tokens, 8 waves (2m x 4n).
// Computes val = W.Act + b; X1[tok] = xres[tok] + gamma*val; LN over 256 ch;
// LNM==1: lnout[wrow] (window order, pads zeroed) ; LNM==2: lnout[tok] (token order).
template <int LNM>
__global__ __launch_bounds__(512, 4) void gemm_ln(
        const unsigned short* __restrict__ Wt,   // [256][256] bf16
        const unsigned short* __restrict__ Act,  // [32768][256] bf16
        const float* __restrict__ bias,
        const float* __restrict__ xres, const float* __restrict__ gammap,
        float* __restrict__ fout,
        const float* __restrict__ lnw, const float* __restrict__ lnb,
        unsigned short* __restrict__ lnout) {
    constexpr int BUFB = 16384 + 8192;           // A 16KB + B 8KB
    __shared__ __align__(16) char pool[3 * BUFB];   // 72KB; Cs (64KB) fits
    unsigned short* Cs = (unsigned short*)pool;

    const int t = threadIdx.x, w = t >> 6, l = t & 63;
    // XCD swizzle over gridDim.x blocks
    int lin = blockIdx.x;
    int T = gridDim.x;
    int q = T >> 3, rr = T & 7;
    int xcd = lin & 7, slot = lin >> 3;
    int wid = (xcd < rr) ? (xcd * (q + 1) + slot)
                         : (rr * (q + 1) + (xcd - rr) * q + slot);
    const int n0 = wid * 128;

    const int wr = w >> 2, wc = w & 3;
    const int r = l & 15, g = l >> 4;
    const int gp = (g ^ ((r >> 1) & 3)) * 8;
    const int K = 256;

    f32x4 acc[8][2];
#pragma unroll
    for (int i = 0; i < 8; ++i)
#pragma unroll
        for (int j = 0; j < 2; ++j) { acc[i][j][0]=0.f; acc[i][j][1]=0.f; acc[i][j][2]=0.f; acc[i][j][3]=0.f; }

#define STAGE(k0, buf)                                                             \
    do {                                                                           \
        _Pragma("unroll")                                                          \
        for (int p = 0; p < 2; ++p) {                                              \
            int c    = p * 512 + t;                                                \
            int rowa = c >> 2;                                                     \
            int gla  = (c & 3) ^ ((rowa >> 1) & 3);                                \
            gl_lds16(Wt + (size_t)rowa * K + (k0) + gla * 8,                       \
                     pool + (buf) * BUFB + (p * 512 + w * 64) * 16);               \
        }                                                                          \
        {                                                                          \
            int rowb = t >> 2;                                                     \
            int glb  = (t & 3) ^ ((rowb >> 1) & 3);                                \
            gl_lds16(Act + (size_t)(n0 + rowb) * K + (k0) + glb * 8,               \
                     pool + (buf) * BUFB + 16384 + w * 1024);                      \
        }                                                                          \
    } while (0)

    STAGE(0, 0);
    STAGE(32, 1);
    const char* cb0 = pool;
    const char* cb1 = pool + BUFB;
    const char* cb2 = pool + 2 * BUFB;
    int sbuf = 2;
    for (int kt = 0; kt < 8; ++kt) {
        if (kt < 7) asm volatile("s_waitcnt vmcnt(3)" ::: "memory");
        else        asm volatile("s_waitcnt vmcnt(0)" ::: "memory");
        __builtin_amdgcn_s_barrier();
        __builtin_amdgcn_sched_barrier(0);
        const unsigned short* cA = (const unsigned short*)cb0;
        const unsigned short* cB = (const unsigned short*)(cb0 + 16384);
        bf16x8 bw[2];
#pragma unroll
        for (int n = 0; n < 2; ++n)
            bw[n] = *reinterpret_cast<const bf16x8*>(&cB[(wc * 32 + n * 16 + r) * 32 + gp]);
        __builtin_amdgcn_s_setprio(1);
#pragma unroll
        for (int m = 0; m < 8; ++m) {
            bf16x8 af = *reinterpret_cast<const bf16x8*>(&cA[(wr * 128 + m * 16 + r) * 32 + gp]);
#pragma unroll
            for (int n = 0; n < 2; ++n)
                acc[m][n] = __builtin_amdgcn_mfma_f32_16x16x32_bf16(af, bw[n], acc[m][n], 0, 0, 0);
        }
        __builtin_amdgcn_s_setprio(0);
        if (kt + 2 < 8) {
            STAGE((kt + 2) * 32, sbuf);
            sbuf = (sbuf == 2) ? 0 : sbuf + 1;
        }
        const char* tmp = cb0; cb0 = cb1; cb1 = cb2; cb2 = tmp;
    }
#undef STAGE

    // ---- epilogue: Cs [128 tok][256 ch], swizzled 8B granules ----
    __syncthreads();
#pragma unroll
    for (int m = 0; m < 8; ++m) {
        const int ch0 = wr * 128 + m * 16 + g * 4;
        float4 b4 = *reinterpret_cast<const float4*>(bias + ch0);
        const float bb[4] = {b4.x, b4.y, b4.z, b4.w};
#pragma unroll
        for (int n = 0; n < 2; ++n) {
            const int tokh = wc * 32 + n * 16 + r;
            ushort4 pk;
            pk.x = f2bf(acc[m][n][0] + bb[0]);
            pk.y = f2bf(acc[m][n][1] + bb[1]);
            pk.z = f2bf(acc[m][n][2] + bb[2]);
            pk.w = f2bf(acc[m][n][3] + bb[3]);
            int gran = (ch0 >> 2) ^ ((tokh & 15) << 1);
            reinterpret_cast<ushort4*>(Cs)[tokh * 64 + gran] = pk;
        }
    }
    __syncthreads();

    const float gsc = gammap[0];
    const int u16 = t & 31, trow = t >> 5;   // 32 lanes per row, 16 rows per pass
#pragma unroll
    for (int it = 0; it < 8; ++it) {
        int rowh = it * 16 + trow;
        int wrow = n0 + rowh;
        // window decode
        int win = wrow >> 6, l2 = wrow & 63;
        int f = win >> 6, wih = (win >> 3) & 7, wiw = win & 7;
        int r2 = l2 >> 3, s2 = l2 & 7;
        int hh = wih * 8 + r2, wcol = wiw * 8 + s2;
        bool pad = (hh >= 60) || (wcol >= 60);
        if (pad) {
            if (LNM == 1) {
                uint4 z = {0u, 0u, 0u, 0u};
                *reinterpret_cast<uint4*>(lnout + (size_t)wrow * CC + u16 * 8) = z;
            }
            continue;
        }
        int oh = hh + 4; if (oh >= 60) oh -= 60;
        int ow = wcol + 4; if (ow >= 60) ow -= 60;
        int tok = f * 3600 + oh * 60 + ow;

        int up = u16 ^ (rowh & 15);
        uint4 v = reinterpret_cast<const uint4*>(Cs)[rowh * 32 + up];
        const unsigned short* pu = (const unsigned short*)&v;
        const float* xr = xres + (size_t)tok * CC + u16 * 8;
        float4 xa = *reinterpret_cast<const float4*>(xr);
        float4 xb = *reinterpret_cast<const float4*>(xr + 4);
        float4 oa, ob;
        oa.x = xa.x + gsc * bf2f(pu[0]);
        oa.y = xa.y + gsc * bf2f(pu[1]);
        oa.z = xa.z + gsc * bf2f(pu[2]);
        oa.w = xa.w + gsc * bf2f(pu[3]);
        ob.x = xb.x + gsc * bf2f(pu[4]);
        ob.y = xb.y + gsc * bf2f(pu[5]);
        ob.z = xb.z + gsc * bf2f(pu[6]);
        ob.w = xb.w + gsc * bf2f(pu[7]);
        float* fo = fout + (size_t)tok * CC + u16 * 8;
        *reinterpret_cast<float4*>(fo) = oa;
        *reinterpret_cast<float4*>(fo + 4) = ob;

        // ---- fused LayerNorm over the 256-ch row (32 lanes cooperate) ----
        float sm = oa.x + oa.y + oa.z + oa.w + ob.x + ob.y + ob.z + ob.w;
        float s2q = oa.x*oa.x + oa.y*oa.y + oa.z*oa.z + oa.w*oa.w
                  + ob.x*ob.x + ob.y*ob.y + ob.z*ob.z + ob.w*ob.w;
#pragma unroll
        for (int off = 1; off <= 16; off <<= 1) {
            sm  += __shfl_xor(sm, off);
            s2q += __shfl_xor(s2q, off);
        }
        float mean = sm * (1.0f / CC);
        float rs   = rsqrtf(s2q * (1.0f / CC) - mean * mean + 1e-5f);
        float4 w0 = *reinterpret_cast<const float4*>(lnw + u16 * 8);
        float4 w1 = *reinterpret_cast<const float4*>(lnw + u16 * 8 + 4);
        float4 c0 = *reinterpret_cast<const float4*>(lnb + u16 * 8);
        float4 c1 = *reinterpret_cast<const float4*>(lnb + u16 * 8 + 4);
        ushort4 pa, pb;
        pa.x = f2bf((oa.x - mean) * rs * w0.x + c0.x);
        pa.y = f2bf((oa.y - mean) * rs * w0.y + c0.y);
        pa.z = f2bf((oa.z - mean) * rs * w0.z + c0.z);
        pa.w = f2bf((oa.w - mean) * rs * w0.w + c0.w);
        pb.x = f2bf((ob.x - mean) * rs * w1.x + c1.x);
        pb.y = f2bf((ob.y - mean) * rs * w1.y + c1.y);
        pb.z = f2bf((ob.z - mean) * rs * w1.z + c1.z);
        pb.w = f2bf((ob.w - mean) * rs * w1.w + c1.w);
        size_t dst = (size_t)((LNM == 1) ? wrow : tok) * CC + u16 * 8;
        *reinterpret_cast<ushort4*>(lnout + dst)     = pa;
        *reinterpret_cast<ushort4*>(lnout + dst + 4) = pb;
    }
}

// ---------------- bias table expansion: biasx[2][8][64][64] ----------------
__global__ void expand_bias(const float* __restrict__ sa, const float* __restrict__ ca,
                            float* __restrict__ dst) {
    int e = (int)(blockIdx.x * blockDim.x + threadIdx.x);   // 0..32767
    const float* src = (e < 16384) ? sa : ca;
    int e2 = e & 16383;
    int h = e2 >> 12, ij = e2 & 4095, i = ij >> 6, j = ij & 63;
    int ri = i >> 3, si = i & 7, rj = j >> 3, sj = j & 7;
    dst[e] = src[((ri - rj + 7) * 15 + (si - sj + 7)) * 8 + h];
}

// ---------------- MFMA attention: one wave per (window, head) ----------------
__global__ __launch_bounds__(256) void attn_mfma(
        const unsigned short* __restrict__ Q,   // [32768][256] bf16
        const unsigned short* __restrict__ K,   // [32768][256] bf16
        const unsigned short* __restrict__ VT,  // [256][32768] bf16
        const float* __restrict__ biasx,        // [8][64][64] f32
        unsigned short* __restrict__ AO) {      // [32768][256] bf16
    __shared__ __align__(16) unsigned short Pl[4][64 * 64];
    const int t = threadIdx.x;
    const int w = t >> 6, l = t & 63;
    const int win = blockIdx.x >> 1;
    const int h   = (blockIdx.x & 1) * 4 + w;
    const int c = l & 15, g = l >> 4;
    const int wih = (win >> 3) & 7, wiw = win & 7;
    const size_t qkbase = (size_t)win * 64 * CC + (size_t)h * 32;

    bf16x8 ka[4], qb[4];
#pragma unroll
    for (int mj = 0; mj < 4; ++mj)
        ka[mj] = *reinterpret_cast<const bf16x8*>(K + qkbase + (size_t)(mj * 16 + c) * CC + g * 8);
#pragma unroll
    for (int ni = 0; ni < 4; ++ni)
        qb[ni] = *reinterpret_cast<const bf16x8*>(Q + qkbase + (size_t)(ni * 16 + c) * CC + g * 8);
    f32x4 s[4][4];
#pragma unroll
    for (int mj = 0; mj < 4; ++mj)
#pragma unroll
        for (int ni = 0; ni < 4; ++ni) { s[mj][ni][0]=0.f; s[mj][ni][1]=0.f; s[mj][ni][2]=0.f; s[mj][ni][3]=0.f; }
#pragma unroll
    for (int mj = 0; mj < 4; ++mj)
#pragma unroll
        for (int ni = 0; ni < 4; ++ni)
            s[mj][ni] = __builtin_amdgcn_mfma_f32_16x16x32_bf16(ka[mj], qb[ni], s[mj][ni], 0, 0, 0);

    const float* bx = biasx + h * 4096;
    const bool modd = (wiw == 7) && (g & 1);
#pragma unroll
    for (int mj = 0; mj < 4; ++mj) {
        const bool mmj = (wih == 7) && (mj >= 2);
#pragma unroll
        for (int ni = 0; ni < 4; ++ni) {
            float4 b4 = *reinterpret_cast<const float4*>(bx + (ni * 16 + c) * 64 + mj * 16 + g * 4);
            const float bb[4] = {b4.x, b4.y, b4.z, b4.w};
#pragma unroll
            for (int jj = 0; jj < 4; ++jj) {
                float v = s[mj][ni][jj] * ATT_SCALE + bb[jj];
                s[mj][ni][jj] = (mmj || modd) ? -1e30f : v;
            }
        }
    }

#pragma unroll
    for (int ni = 0; ni < 4; ++ni) {
        float mx = -1e30f;
#pragma unroll
        for (int mj = 0; mj < 4; ++mj)
#pragma unroll
            for (int jj = 0; jj < 4; ++jj) mx = fmaxf(mx, s[mj][ni][jj]);
        mx = fmaxf(mx, __shfl_xor(mx, 16));
        mx = fmaxf(mx, __shfl_xor(mx, 32));
        float sum = 0.f;
#pragma unroll
        for (int mj = 0; mj < 4; ++mj)
#pragma unroll
            for (int jj = 0; jj < 4; ++jj) {
                float p = __expf(s[mj][ni][jj] - mx);
                s[mj][ni][jj] = p;
                sum += p;
            }
        sum += __shfl_xor(sum, 16);
        sum += __shfl_xor(sum, 32);
        float rinv = __builtin_amdgcn_rcpf(sum);
        const int i  = ni * 16 + c;
        const int ik = i & 7;
#pragma unroll
        for (int mj = 0; mj < 4; ++mj) {
            ushort4 pk;
            pk.x = f2bf(s[mj][ni][0] * rinv);
            pk.y = f2bf(s[mj][ni][1] * rinv);
            pk.z = f2bf(s[mj][ni][2] * rinv);
            pk.w = f2bf(s[mj][ni][3] * rinv);
            int chunk = (mj * 2 + (g >> 1)) ^ ik;
            *reinterpret_cast<ushort4*>((char*)&Pl[w][0] + i * 128 + chunk * 16 + (g & 1) * 8) = pk;
        }
    }

    bf16x8 vb[2][2];
#pragma unroll
    for (int nd = 0; nd < 2; ++nd)
#pragma unroll
        for (int kt = 0; kt < 2; ++kt)
            vb[nd][kt] = *reinterpret_cast<const bf16x8*>(
                VT + (size_t)(h * 32 + nd * 16 + c) * 32768 + win * 64 + kt * 32 + g * 8);
    f32x4 o[4][2];
#pragma unroll
    for (int mi = 0; mi < 4; ++mi)
#pragma unroll
        for (int nd = 0; nd < 2; ++nd) { o[mi][nd][0]=0.f; o[mi][nd][1]=0.f; o[mi][nd][2]=0.f; o[mi][nd][3]=0.f; }
#pragma unroll
    for (int mi = 0; mi < 4; ++mi) {
        const int i  = mi * 16 + c;
        const int ik = i & 7;
#pragma unroll
        for (int kt = 0; kt < 2; ++kt) {
            int chunk = (kt * 4 + g) ^ ik;
            bf16x8 pa = *reinterpret_cast<const bf16x8*>((char*)&Pl[w][0] + i * 128 + chunk * 16);
#pragma unroll
            for (int nd = 0; nd < 2; ++nd)
                o[mi][nd] = __builtin_amdgcn_mfma_f32_16x16x32_bf16(pa, vb[nd][kt], o[mi][nd], 0, 0, 0);
        }
    }

    unsigned short* aop = AO + qkbase;
#pragma unroll
    for (int mi = 0; mi < 4; ++mi)
#pragma unroll
        for (int nd = 0; nd < 2; ++nd)
#pragma unroll
            for (int jj = 0; jj < 4; ++jj)
                aop[(size_t)(mi * 16 + g * 4 + jj) * CC + nd * 16 + c] = f2bf(o[mi][nd][jj]);
}

// ---------------- weight fp32 -> bf16 conversion ----------------
__global__ void cvt_all(const float* s0, const float* s1, const float* s2, const float* s3,
                        const float* s4, const float* s5, const float* s6, const float* s7,
                        const float* s8, const float* s9, unsigned short* __restrict__ dst) {
    const float* srcs[10] = {s0, s1, s2, s3, s4, s5, s6, s7, s8, s9};
    int blk = blockIdx.x;
    int wi = (blk < 512) ? (blk >> 6) : (blk < 768 ? 8 : 9);
    size_t start = (wi < 8) ? (size_t)wi * 65536 : (wi == 8 ? (size_t)524288 : (size_t)786432);
    size_t gidx = (size_t)blk * 1024 + (size_t)threadIdx.x * 4;
    float4 v = *reinterpret_cast<const float4*>(srcs[wi] + (gidx - start));
    ushort4 o;
    o.x = f2bf(v.x); o.y = f2bf(v.y); o.z = f2bf(v.z); o.w = f2bf(v.w);
    *reinterpret_cast<ushort4*>(dst + gidx) = o;
}

extern "C" void kernel_launch(void* const* d_in, const int* in_sizes, int n_in,
                              void* d_out, int out_size, void* d_ws, size_t ws_size,
                              hipStream_t stream) {
    const float* x    = (const float*)d_in[0];
    const float* ctx  = (const float*)d_in[1];
    const float* ln1w = (const float*)d_in[2];
    const float* ln1b = (const float*)d_in[3];
    const float* ln2w = (const float*)d_in[4];
    const float* ln2b = (const float*)d_in[5];
    const float* ln3w = (const float*)d_in[6];
    const float* ln3b = (const float*)d_in[7];
    const float* lncw = (const float*)d_in[8];
    const float* lncb = (const float*)d_in[9];
    const float* saqw = (const float*)d_in[10];
    const float* saqb = (const float*)d_in[11];
    const float* sakw = (const float*)d_in[12];
    const float* sakb = (const float*)d_in[13];
    const float* savw = (const float*)d_in[14];
    const float* savb = (const float*)d_in[15];
    const float* saow = (const float*)d_in[16];
    const float* saob = (const float*)d_in[17];
    const float* sabias = (const float*)d_in[18];
    const float* caqw = (const float*)d_in[19];
    const float* caqb = (const float*)d_in[20];
    const float* cakw = (const float*)d_in[21];
    const float* cakb = (const float*)d_in[22];
    const float* cavw = (const float*)d_in[23];
    const float* cavb = (const float*)d_in[24];
    const float* caow = (const float*)d_in[25];
    const float* caob = (const float*)d_in[26];
    const float* cabias = (const float*)d_in[27];
    const float* gamma1 = (const float*)d_in[28];
    const float* gamma2 = (const float*)d_in[29];
    const float* gammam = (const float*)d_in[30];
    const float* mw1 = (const float*)d_in[31];
    const float* mb1 = (const float*)d_in[32];
    const float* mw2 = (const float*)d_in[33];
    const float* mb2 = (const float*)d_in[34];

    float* ws = (float*)d_ws;
    unsigned short* LNbf = (unsigned short*)(ws);                 // 3,686,400 f
    unsigned short* Gq   = (unsigned short*)(ws + 3686400);       // 4,194,304 f
    unsigned short* Gkv  = (unsigned short*)(ws + 7880704);       // 4,194,304 f
    unsigned short* Qbf  = (unsigned short*)(ws + 12075008);      // 4,194,304 f
    unsigned short* Kbf  = (unsigned short*)(ws + 16269312);      // 4,194,304 f
    unsigned short* VTbf = (unsigned short*)(ws + 20463616);      // 4,194,304 f
    unsigned short* AObf = (unsigned short*)(ws + 24657920);      // 4,194,304 f (own slot now)
    float* X1  = ws + 28852224;                                   // 7,372,800 f
    unsigned short* Wp = (unsigned short*)(ws + 36225024);        // 524,288 f
    float* biasx = ws + 36749312;                                 // 32,768 f
    unsigned short* H1bf = Qbf;                                   // alias (Q/K/VT/AO dead in MLP phase)

    // cvt layout (contiguous): saq|sak|sav | sao | caq | cak|cav | cao | m1 | m2
    unsigned short* w_saqkv = Wp;                                 // [768][256]
    unsigned short* w_sao   = Wp + 196608;                        // [256][256]
    unsigned short* w_caq   = Wp + 262144;                        // [256][256]
    unsigned short* w_cakv  = Wp + 327680;                        // [512][256]
    unsigned short* w_cao   = Wp + 458752;                        // [256][256]
    unsigned short* w_m1    = Wp + 524288;                        // [1024][256]
    unsigned short* w_m2    = Wp + 786432;                        // [256][1024]

    float* OUT = (float*)d_out;

    dim3 blk(256);
    dim3 blk512(512);
    dim3 gGather(WROWS / 4);
    dim3 gAttn(WINS * 2);

    cvt_all<<<dim3(1024), blk, 0, stream>>>(saqw, sakw, savw, saow, caqw, cakw, cavw, caow, mw1, mw2, Wp);
    expand_bias<<<dim3(128), blk, 0, stream>>>(sabias, cabias, biasx);

    // ---- self attention ----
    ln_gather<<<gGather, blk, 0, stream>>>(x, ln1w, ln1b, Gq);
    gemm_wa<false,0,256><<<dim3(6, 128), blk512, 0, stream>>>(w_saqkv, Gq, saqb, sakb, savb, savb,
                                                              Qbf, Kbf, VTbf, VTbf, CC, 2, CC, WROWS,
                                                              nullptr, nullptr, nullptr);
    attn_mfma<<<gAttn, blk, 0, stream>>>(Qbf, Kbf, VTbf, biasx, AObf);
    // sao + residual(x) + LN2 + window re-gather -> Gq (window order)
    gemm_ln<1><<<dim3(256), blk512, 0, stream>>>(w_sao, AObf, saob, x, gamma1, X1, ln2w, ln2b, Gq);

    // ---- cross attention ----
    ln_gather<<<gGather, blk, 0, stream>>>(ctx, lncw, lncb, Gkv);
    gemm_wa<false,0,128><<<dim3(2, 256), blk512, 0, stream>>>(w_caq, Gq, caqb, caqb, caqb, caqb,
                                                              Qbf, Qbf, Qbf, Qbf, CC, -1, CC, WROWS,
                                                              nullptr, nullptr, nullptr);
    gemm_wa<false,0,256><<<dim3(4, 128), blk512, 0, stream>>>(w_cakv, Gkv, cakb, cavb, cavb, cavb,
                                                              Kbf, VTbf, VTbf, VTbf, CC, 1, CC, WROWS,
                                                              nullptr, nullptr, nullptr);
    attn_mfma<<<gAttn, blk, 0, stream>>>(Qbf, Kbf, VTbf, biasx + 16384, AObf);
    // cao + residual(X1, in place) + LN3 -> LNbf (token order)
    gemm_ln<2><<<dim3(256), blk512, 0, stream>>>(w_cao, AObf, caob, X1, gamma2, X1, ln3w, ln3b, LNbf);

    // ---- MLP ----
    gemm_wa<true,0,256><<<dim3(8, 113), blk512, 0, stream>>>(w_m1, LNbf, mb1, mb1 + 256, mb1 + 512, mb1 + 768,
                                                             H1bf, H1bf + 256, H1bf + 512, H1bf + 768,
                                                             HIDN, -1, CC, BN, nullptr, nullptr, nullptr);
    gemm_wa<false,2,256><<<dim3(2, 113), blk512, 0, stream>>>(w_m2, H1bf, mb2, mb2, mb2, mb2,
                                                             Qbf, Qbf, Qbf, Qbf, CC, -1, HIDN, BN,
                                                             X1, gammam, OUT);
}

// Round 14
// 213.154 us; speedup vs baseline: 1.2380x; 1.0563x over previous
//
#include <hip/hip_runtime.h>
#include <math.h>

// ---- problem constants ----
#define BN    28800      // B*N tokens total
#define CC    256        // channels
#define HIDN  1024       // MLP hidden
#define WINS  512        // total windows (8 frames * 64)
#define WROWS (WINS*64)  // 32768 window rows
#define ATT_SCALE 0.1767766952966369f

typedef __bf16 bf16x8 __attribute__((ext_vector_type(8)));
typedef float  f32x4  __attribute__((ext_vector_type(4)));

__device__ __forceinline__ unsigned short f2bf(float f) {
    unsigned u = __float_as_uint(f);
    unsigned r = (u + 0x7FFFu + ((u >> 16) & 1u)) >> 16;
    return (unsigned short)r;
}
__device__ __forceinline__ float bf2f(unsigned short u) {
    return __uint_as_float((unsigned)u << 16);
}

// fast GELU (tanh form) with fast rcp; overflow-safe
__device__ __forceinline__ float gelu_f(float x) {
    float x3 = x * x * x;
    float e  = __expf(1.5957691216057308f * (x + 0.044715f * x3));  // exp(2y)
    float th = 1.0f - 2.0f * __builtin_amdgcn_rcpf(e + 1.0f);
    return 0.5f * x * (1.0f + th);
}

__device__ __forceinline__ void gl_lds16(const void* g, void* l) {
    __builtin_amdgcn_global_load_lds(
        (const __attribute__((address_space(1))) void*)g,
        (__attribute__((address_space(3))) void*)l, 16, 0, 0);
}

// ---------------- fused LayerNorm + window gather, two inputs in one launch ----------
__global__ void ln_gather2(const float* __restrict__ x,   const float* __restrict__ w1,
                           const float* __restrict__ b1,  unsigned short* __restrict__ d1,
                           const float* __restrict__ ctx, const float* __restrict__ wc,
                           const float* __restrict__ bc,  unsigned short* __restrict__ d2) {
    const int half = blockIdx.x >> 13;                       // 8192 blocks per half
    const float* src = half ? ctx : x;
    const float* w   = half ? wc  : w1;
    const float* b   = half ? bc  : b1;
    unsigned short* dst = half ? d2 : d1;
    int row  = (int)((((blockIdx.x & 8191) * blockDim.x) + threadIdx.x) >> 6);
    int lane = threadIdx.x & 63;
    if (row >= WROWS) return;
    int win = row >> 6, l = row & 63;
    int f   = win >> 6;
    int wih = (win >> 3) & 7, wiw = win & 7;
    int r = l >> 3, s = l & 7;
    int h = wih * 8 + r, wc2 = wiw * 8 + s;
    if (h >= 60 || wc2 >= 60) {
        ushort4 z = {0, 0, 0, 0};
        reinterpret_cast<ushort4*>(dst + (size_t)row * CC)[lane] = z;
        return;
    }
    int oh = (h + 4) % 60, ow = (wc2 + 4) % 60;
    size_t tok = (size_t)f * 3600 + (size_t)oh * 60 + ow;
    float4 v = reinterpret_cast<const float4*>(src + tok * CC)[lane];
    float sm  = v.x + v.y + v.z + v.w;
    float s2 = v.x*v.x + v.y*v.y + v.z*v.z + v.w*v.w;
#pragma unroll
    for (int off = 32; off >= 1; off >>= 1) {
        sm += __shfl_xor(sm, off);
        s2 += __shfl_xor(s2, off);
    }
    float mean = sm * (1.0f / CC);
    float var  = s2 * (1.0f / CC) - mean * mean;
    float rs   = rsqrtf(var + 1e-5f);
    float4 wv = reinterpret_cast<const float4*>(w)[lane];
    float4 bv = reinterpret_cast<const float4*>(b)[lane];
    ushort4 o;
    o.x = f2bf((v.x - mean) * rs * wv.x + bv.x);
    o.y = f2bf((v.y - mean) * rs * wv.y + bv.y);
    o.z = f2bf((v.z - mean) * rs * wv.z + bv.z);
    o.w = f2bf((v.w - mean) * rs * wv.w + bv.w);
    reinterpret_cast<ushort4*>(dst + (size_t)row * CC)[lane] = o;
}

// ---------------- bf16 MFMA GEMM: 512 threads, 8 waves (2x4), 128xTN tile ----------------
// 3-buffer LDS, stage 2 ahead, one barrier per K-step; per-256-ch-segment Act routing.
// FUSE: 0 = bf16 out [tok][strideO] (vseg segment stores V^T [ch][32768]);
//       2 = f32 plain residual out.
template <bool GELU, int FUSE, int TN>
__global__ __launch_bounds__(512, 4) void gemm_wa(
        const unsigned short* __restrict__ Wt,   // [Mtot][K] bf16
        const unsigned short* __restrict__ a0c,  // Act for seg 0
        const unsigned short* __restrict__ a1c,  // Act for seg 1
        const unsigned short* __restrict__ a2c,  // Act for seg >= 2
        const float* __restrict__ b0, const float* __restrict__ b1,
        const float* __restrict__ b2, const float* __restrict__ b3,
        unsigned short* __restrict__ o0, unsigned short* __restrict__ o1,
        unsigned short* __restrict__ o2, unsigned short* __restrict__ o3,
        int strideO, int vseg, int K, int Ntok,
        const float* __restrict__ xres, const float* __restrict__ gammap,
        float* __restrict__ fout) {
    constexpr int NW   = TN / 64;               // 16-col fragments per wave (2 or 4)
    constexpr int BP   = TN / 128;              // B staging passes per step
    constexpr int BUFB = 8192 + TN * 64;        // bytes per stage buffer (A + B)
    constexpr int POOLB = (3 * BUFB > TN * 256) ? 3 * BUFB : TN * 256;
    __shared__ __align__(16) char pool[POOLB];
    unsigned short* Cs = (unsigned short*)pool;

    const int t = threadIdx.x;          // 0..511
    const int w = t >> 6;               // 0..7
    const int l = t & 63;
    // ---- bijective XCD swizzle: m fastest within an XCD ----
    const int Mb = gridDim.x;
    int lin = blockIdx.y * Mb + blockIdx.x;
    int T = Mb * gridDim.y;
    int q = T >> 3, rr = T & 7;
    int xcd = lin & 7, slot = lin >> 3;
    int wid = (xcd < rr) ? (xcd * (q + 1) + slot)
                         : (rr * (q + 1) + (xcd - rr) * q + slot);
    const int m0 = (wid % Mb) * 128;
    const int n0 = (wid / Mb) * TN;

    const int seg = m0 >> 8;
    const unsigned short* Act = (seg == 0) ? a0c : (seg == 1) ? a1c : a2c;

    const int wr = w >> 2, wc = w & 3;  // wave tile: rows wr*64, cols wc*(NW*16)
    const int r = l & 15, g = l >> 4;
    const int gp = (g ^ ((r >> 1) & 3)) * 8;
    const int srow = t >> 2;
    const int sgl  = (t & 3) ^ ((srow >> 1) & 3);

    f32x4 acc[4][NW];
#pragma unroll
    for (int i = 0; i < 4; ++i)
#pragma unroll
        for (int j = 0; j < NW; ++j) { acc[i][j][0]=0.f; acc[i][j][1]=0.f; acc[i][j][2]=0.f; acc[i][j][3]=0.f; }

#define STAGE(k0, buf)                                                             \
    do {                                                                           \
        gl_lds16(Wt + (size_t)(m0 + srow) * K + (k0) + sgl * 8,                    \
                 pool + (buf) * BUFB + w * 1024);                                  \
        _Pragma("unroll")                                                          \
        for (int p = 0; p < BP; ++p) {                                             \
            int c    = p * 512 + t;                                                \
            int rowb = c >> 2;                                                     \
            int glb  = (c & 3) ^ ((rowb >> 1) & 3);                                \
            gl_lds16(Act + (size_t)(n0 + rowb) * K + (k0) + glb * 8,               \
                     pool + (buf) * BUFB + 8192 + p * 8192 + w * 1024);            \
        }                                                                          \
    } while (0)

    STAGE(0, 0);
    STAGE(32, 1);
    const char* cb0 = pool;
    const char* cb1 = pool + BUFB;
    const char* cb2 = pool + 2 * BUFB;
    int sbuf = 2;
    const int nt = K >> 5;
    for (int kt = 0; kt < nt; ++kt) {
        if (kt < nt - 1) {
            if (TN == 128) asm volatile("s_waitcnt vmcnt(2)" ::: "memory");
            else           asm volatile("s_waitcnt vmcnt(3)" ::: "memory");
        } else {
            asm volatile("s_waitcnt vmcnt(0)" ::: "memory");
        }
        __builtin_amdgcn_s_barrier();
        __builtin_amdgcn_sched_barrier(0);
        const unsigned short* cA = (const unsigned short*)cb0;
        const unsigned short* cB = (const unsigned short*)(cb0 + 8192);
        bf16x8 bw[NW];
#pragma unroll
        for (int n = 0; n < NW; ++n)
            bw[n] = *reinterpret_cast<const bf16x8*>(&cB[(wc * (NW * 16) + n * 16 + r) * 32 + gp]);
        __builtin_amdgcn_s_setprio(1);
#pragma unroll
        for (int m = 0; m < 4; ++m) {
            bf16x8 af = *reinterpret_cast<const bf16x8*>(&cA[(wr * 64 + m * 16 + r) * 32 + gp]);
#pragma unroll
            for (int n = 0; n < NW; ++n)
                acc[m][n] = __builtin_amdgcn_mfma_f32_16x16x32_bf16(af, bw[n], acc[m][n], 0, 0, 0);
        }
        __builtin_amdgcn_s_setprio(0);
        if (kt + 2 < nt) {
            STAGE((kt + 2) * 32, sbuf);
            sbuf = (sbuf == 2) ? 0 : sbuf + 1;
        }
        const char* tmp = cb0; cb0 = cb1; cb1 = cb2; cb2 = tmp;
    }
#undef STAGE

    // ---- epilogue ----
    const float* bp = (seg == 0) ? b0 : (seg == 1) ? b1 : (seg == 2) ? b2 : b3;
    unsigned short* op = (seg == 0) ? o0 : (seg == 1) ? o1 : (seg == 2) ? o2 : o3;
    const int chseg = m0 & 255;

    if (FUSE == 0 && seg == vseg) {
        // direct transposed store [ch][32768] (V^T for attention)
#pragma unroll
        for (int m = 0; m < 4; ++m) {
            const int ch0 = chseg + wr * 64 + m * 16 + g * 4;
            float4 b4 = *reinterpret_cast<const float4*>(bp + ch0);
            const float bb[4] = {b4.x, b4.y, b4.z, b4.w};
#pragma unroll
            for (int n = 0; n < NW; ++n) {
                const int tok = n0 + wc * (NW * 16) + n * 16 + r;
#pragma unroll
                for (int j = 0; j < 4; ++j)
                    op[(size_t)(ch0 + j) * 32768 + tok] = f2bf(acc[m][n][j] + bb[j]);
            }
        }
        return;
    }

    __syncthreads();   // all waves done with final ds_reads before Cs overwrite
#pragma unroll
    for (int m = 0; m < 4; ++m) {
        const int ch0 = wr * 64 + m * 16 + g * 4;       // local 0..127
        float4 b4 = *reinterpret_cast<const float4*>(bp + chseg + ch0);
        const float bb[4] = {b4.x, b4.y, b4.z, b4.w};
#pragma unroll
        for (int n = 0; n < NW; ++n) {
            const int tok_l = wc * (NW * 16) + n * 16 + r;   // local 0..TN-1
            float cv[4];
#pragma unroll
            for (int j = 0; j < 4; ++j) {
                cv[j] = acc[m][n][j] + bb[j];
                if (GELU) cv[j] = gelu_f(cv[j]);
            }
            ushort4 pk;
            pk.x = f2bf(cv[0]); pk.y = f2bf(cv[1]); pk.z = f2bf(cv[2]); pk.w = f2bf(cv[3]);
            int gran = (ch0 >> 2) ^ ((tok_l & 15) << 1);
            reinterpret_cast<ushort4*>(Cs)[tok_l * 32 + gran] = pk;
        }
    }
    __syncthreads();
    const int u = t & 15, trow = t >> 4;   // trow 0..31
    if (FUSE == 0) {
#pragma unroll
        for (int it = 0; it < TN / 32; ++it) {
            int tok_l = it * 32 + trow;
            if (n0 + tok_l >= Ntok) continue;
            int up = u ^ (tok_l & 15);
            uint4 v = reinterpret_cast<const uint4*>(Cs)[tok_l * 16 + up];
            *reinterpret_cast<uint4*>(op + (size_t)(n0 + tok_l) * strideO + chseg + u * 8) = v;
        }
    } else {
        const float gsc = gammap[0];
#pragma unroll
        for (int it = 0; it < TN / 32; ++it) {
            int tok_l = it * 32 + trow;
            int wrow = n0 + tok_l;
            if (wrow >= Ntok) continue;
            int tok = wrow;
            int up = u ^ (tok_l & 15);
            uint4 v = reinterpret_cast<const uint4*>(Cs)[tok_l * 16 + up];
            const unsigned short* pu = (const unsigned short*)&v;
            const float* xr = xres + (size_t)tok * CC + chseg + u * 8;
            float4 xa = *reinterpret_cast<const float4*>(xr);
            float4 xb = *reinterpret_cast<const float4*>(xr + 4);
            float4 oa, ob;
            oa.x = xa.x + gsc * bf2f(pu[0]);
            oa.y = xa.y + gsc * bf2f(pu[1]);
            oa.z = xa.z + gsc * bf2f(pu[2]);
            oa.w = xa.w + gsc * bf2f(pu[3]);
            ob.x = xb.x + gsc * bf2f(pu[4]);
            ob.y = xb.y + gsc * bf2f(pu[5]);
            ob.z = xb.z + gsc * bf2f(pu[6]);
            ob.w = xb.w + gsc * bf2f(pu[7]);
            float* fo = fout + (size_t)tok * CC + chseg + u * 8;
            *reinterpret_cast<float4*>(fo) = oa;
            *reinterpret_cast<float4*>(fo + 4) = ob;
        }
    }
}

// ---------------- o-proj GEMM with fused residual + LayerNorm output ----------------
// M = 256 (full channels, one m-block), TN = 128 tokens, 8 waves (2m x 4n).
// LNM==1: lnout[wrow] (window order, pads zeroed) ; LNM==2: lnout[tok] (token order).
template <int LNM>
__global__ __launch_bounds__(512, 4) void gemm_ln(
        const unsigned short* __restrict__ Wt,   // [256][256] bf16
        const unsigned short* __restrict__ Act,  // [32768][256] bf16
        const float* __restrict__ bias,
        const float* __restrict__ xres, const float* __restrict__ gammap,
        float* __restrict__ fout,
        const float* __restrict__ lnw, const float* __restrict__ lnb,
        unsigned short* __restrict__ lnout) {
    constexpr int BUFB = 16384 + 8192;           // A 16KB + B 8KB
    __shared__ __align__(16) char pool[3 * BUFB];   // 72KB; Cs (64KB) fits
    unsigned short* Cs = (unsigned short*)pool;

    const int t = threadIdx.x, w = t >> 6, l = t & 63;
    int lin = blockIdx.x;
    int T = gridDim.x;
    int q = T >> 3, rr = T & 7;
    int xcd = lin & 7, slot = lin >> 3;
    int wid = (xcd < rr) ? (xcd * (q + 1) + slot)
                         : (rr * (q + 1) + (xcd - rr) * q + slot);
    const int n0 = wid * 128;

    const int wr = w >> 2, wc = w & 3;
    const int r = l & 15, g = l >> 4;
    const int gp = (g ^ ((r >> 1) & 3)) * 8;
    const int K = 256;

    f32x4 acc[8][2];
#pragma unroll
    for (int i = 0; i < 8; ++i)
#pragma unroll
        for (int j = 0; j < 2; ++j) { acc[i][j][0]=0.f; acc[i][j][1]=0.f; acc[i][j][2]=0.f; acc[i][j][3]=0.f; }

#define STAGE(k0, buf)                                                             \
    do {                                                                           \
        _Pragma("unroll")                                                          \
        for (int p = 0; p < 2; ++p) {                                              \
            int c    = p * 512 + t;                                                \
            int rowa = c >> 2;                                                     \
            int gla  = (c & 3) ^ ((rowa >> 1) & 3);                                \
            gl_lds16(Wt + (size_t)rowa * K + (k0) + gla * 8,                       \
                     pool + (buf) * BUFB + (p * 512 + w * 64) * 16);               \
        }                                                                          \
        {                                                                          \
            int rowb = t >> 2;                                                     \
            int glb  = (t & 3) ^ ((rowb >> 1) & 3);                                \
            gl_lds16(Act + (size_t)(n0 + rowb) * K + (k0) + glb * 8,               \
                     pool + (buf) * BUFB + 16384 + w * 1024);                      \
        }                                                                          \
    } while (0)

    STAGE(0, 0);
    STAGE(32, 1);
    const char* cb0 = pool;
    const char* cb1 = pool + BUFB;
    const char* cb2 = pool + 2 * BUFB;
    int sbuf = 2;
    for (int kt = 0; kt < 8; ++kt) {
        if (kt < 7) asm volatile("s_waitcnt vmcnt(3)" ::: "memory");
        else        asm volatile("s_waitcnt vmcnt(0)" ::: "memory");
        __builtin_amdgcn_s_barrier();
        __builtin_amdgcn_sched_barrier(0);
        const unsigned short* cA = (const unsigned short*)cb0;
        const unsigned short* cB = (const unsigned short*)(cb0 + 16384);
        bf16x8 bw[2];
#pragma unroll
        for (int n = 0; n < 2; ++n)
            bw[n] = *reinterpret_cast<const bf16x8*>(&cB[(wc * 32 + n * 16 + r) * 32 + gp]);
        __builtin_amdgcn_s_setprio(1);
#pragma unroll
        for (int m = 0; m < 8; ++m) {
            bf16x8 af = *reinterpret_cast<const bf16x8*>(&cA[(wr * 128 + m * 16 + r) * 32 + gp]);
#pragma unroll
            for (int n = 0; n < 2; ++n)
                acc[m][n] = __builtin_amdgcn_mfma_f32_16x16x32_bf16(af, bw[n], acc[m][n], 0, 0, 0);
        }
        __builtin_amdgcn_s_setprio(0);
        if (kt + 2 < 8) {
            STAGE((kt + 2) * 32, sbuf);
            sbuf = (sbuf == 2) ? 0 : sbuf + 1;
        }
        const char* tmp = cb0; cb0 = cb1; cb1 = cb2; cb2 = tmp;
    }
#undef STAGE

    // ---- epilogue: Cs [128 tok][256 ch], swizzled 8B granules ----
    __syncthreads();
#pragma unroll
    for (int m = 0; m < 8; ++m) {
        const int ch0 = wr * 128 + m * 16 + g * 4;
        float4 b4 = *reinterpret_cast<const float4*>(bias + ch0);
        const float bb[4] = {b4.x, b4.y, b4.z, b4.w};
#pragma unroll
        for (int n = 0; n < 2; ++n) {
            const int tokh = wc * 32 + n * 16 + r;
            ushort4 pk;
            pk.x = f2bf(acc[m][n][0] + bb[0]);
            pk.y = f2bf(acc[m][n][1] + bb[1]);
            pk.z = f2bf(acc[m][n][2] + bb[2]);
            pk.w = f2bf(acc[m][n][3] + bb[3]);
            int gran = (ch0 >> 2) ^ ((tokh & 15) << 1);
            reinterpret_cast<ushort4*>(Cs)[tokh * 64 + gran] = pk;
        }
    }
    __syncthreads();

    const float gsc = gammap[0];
    const int u16 = t & 31, trow = t >> 5;   // 32 lanes per row, 16 rows per pass
#pragma unroll
    for (int it = 0; it < 8; ++it) {
        int rowh = it * 16 + trow;
        int wrow = n0 + rowh;
        int win = wrow >> 6, l2 = wrow & 63;
        int f = win >> 6, wih = (win >> 3) & 7, wiw = win & 7;
        int r2 = l2 >> 3, s2 = l2 & 7;
        int hh = wih * 8 + r2, wcol = wiw * 8 + s2;
        bool pad = (hh >= 60) || (wcol >= 60);
        if (pad) {
            if (LNM == 1) {
                uint4 z = {0u, 0u, 0u, 0u};
                *reinterpret_cast<uint4*>(lnout + (size_t)wrow * CC + u16 * 8) = z;
            }
            continue;
        }
        int oh = hh + 4; if (oh >= 60) oh -= 60;
        int ow = wcol + 4; if (ow >= 60) ow -= 60;
        int tok = f * 3600 + oh * 60 + ow;

        int up = u16 ^ (rowh & 15);
        uint4 v = reinterpret_cast<const uint4*>(Cs)[rowh * 32 + up];
        const unsigned short* pu = (const unsigned short*)&v;
        const float* xr = xres + (size_t)tok * CC + u16 * 8;
        float4 xa = *reinterpret_cast<const float4*>(xr);
        float4 xb = *reinterpret_cast<const float4*>(xr + 4);
        float4 oa, ob;
        oa.x = xa.x + gsc * bf2f(pu[0]);
        oa.y = xa.y + gsc * bf2f(pu[1]);
        oa.z = xa.z + gsc * bf2f(pu[2]);
        oa.w = xa.w + gsc * bf2f(pu[3]);
        ob.x = xb.x + gsc * bf2f(pu[4]);
        ob.y = xb.y + gsc * bf2f(pu[5]);
        ob.z = xb.z + gsc * bf2f(pu[6]);
        ob.w = xb.w + gsc * bf2f(pu[7]);
        float* fo = fout + (size_t)tok * CC + u16 * 8;
        *reinterpret_cast<float4*>(fo) = oa;
        *reinterpret_cast<float4*>(fo + 4) = ob;

        float sm = oa.x + oa.y + oa.z + oa.w + ob.x + ob.y + ob.z + ob.w;
        float s2q = oa.x*oa.x + oa.y*oa.y + oa.z*oa.z + oa.w*oa.w
                  + ob.x*ob.x + ob.y*ob.y + ob.z*ob.z + ob.w*ob.w;
#pragma unroll
        for (int off = 1; off <= 16; off <<= 1) {
            sm  += __shfl_xor(sm, off);
            s2q += __shfl_xor(s2q, off);
        }
        float mean = sm * (1.0f / CC);
        float rs   = rsqrtf(s2q * (1.0f / CC) - mean * mean + 1e-5f);
        float4 w0 = *reinterpret_cast<const float4*>(lnw + u16 * 8);
        float4 w1 = *reinterpret_cast<const float4*>(lnw + u16 * 8 + 4);
        float4 c0 = *reinterpret_cast<const float4*>(lnb + u16 * 8);
        float4 c1 = *reinterpret_cast<const float4*>(lnb + u16 * 8 + 4);
        ushort4 pa, pb;
        pa.x = f2bf((oa.x - mean) * rs * w0.x + c0.x);
        pa.y = f2bf((oa.y - mean) * rs * w0.y + c0.y);
        pa.z = f2bf((oa.z - mean) * rs * w0.z + c0.z);
        pa.w = f2bf((oa.w - mean) * rs * w0.w + c0.w);
        pb.x = f2bf((ob.x - mean) * rs * w1.x + c1.x);
        pb.y = f2bf((ob.y - mean) * rs * w1.y + c1.y);
        pb.z = f2bf((ob.z - mean) * rs * w1.z + c1.z);
        pb.w = f2bf((ob.w - mean) * rs * w1.w + c1.w);
        size_t dst = (size_t)((LNM == 1) ? wrow : tok) * CC + u16 * 8;
        *reinterpret_cast<ushort4*>(lnout + dst)     = pa;
        *reinterpret_cast<ushort4*>(lnout + dst + 4) = pb;
    }
}

// ---------------- MFMA attention: one wave per (window, head) ----------------
__global__ __launch_bounds__(256) void attn_mfma(
        const unsigned short* __restrict__ Q,   // [32768][256] bf16
        const unsigned short* __restrict__ K,   // [32768][256] bf16
        const unsigned short* __restrict__ VT,  // [256][32768] bf16
        const float* __restrict__ biasx,        // [8][64][64] f32
        unsigned short* __restrict__ AO) {      // [32768][256] bf16
    __shared__ __align__(16) unsigned short Pl[4][64 * 64];
    const int t = threadIdx.x;
    const int w = t >> 6, l = t & 63;
    const int win = blockIdx.x >> 1;
    const int h   = (blockIdx.x & 1) * 4 + w;
    const int c = l & 15, g = l >> 4;
    const int wih = (win >> 3) & 7, wiw = win & 7;
    const size_t qkbase = (size_t)win * 64 * CC + (size_t)h * 32;

    bf16x8 ka[4], qb[4];
#pragma unroll
    for (int mj = 0; mj < 4; ++mj)
        ka[mj] = *reinterpret_cast<const bf16x8*>(K + qkbase + (size_t)(mj * 16 + c) * CC + g * 8);
#pragma unroll
    for (int ni = 0; ni < 4; ++ni)
        qb[ni] = *reinterpret_cast<const bf16x8*>(Q + qkbase + (size_t)(ni * 16 + c) * CC + g * 8);
    f32x4 s[4][4];
#pragma unroll
    for (int mj = 0; mj < 4; ++mj)
#pragma unroll
        for (int ni = 0; ni < 4; ++ni) { s[mj][ni][0]=0.f; s[mj][ni][1]=0.f; s[mj][ni][2]=0.f; s[mj][ni][3]=0.f; }
#pragma unroll
    for (int mj = 0; mj < 4; ++mj)
#pragma unroll
        for (int ni = 0; ni < 4; ++ni)
            s[mj][ni] = __builtin_amdgcn_mfma_f32_16x16x32_bf16(ka[mj], qb[ni], s[mj][ni], 0, 0, 0);

    const float* bx = biasx + h * 4096;
    const bool modd = (wiw == 7) && (g & 1);
#pragma unroll
    for (int mj = 0; mj < 4; ++mj) {
        const bool mmj = (wih == 7) && (mj >= 2);
#pragma unroll
        for (int ni = 0; ni < 4; ++ni) {
            float4 b4 = *reinterpret_cast<const float4*>(bx + (ni * 16 + c) * 64 + mj * 16 + g * 4);
            const float bb[4] = {b4.x, b4.y, b4.z, b4.w};
#pragma unroll
            for (int jj = 0; jj < 4; ++jj) {
                float v = s[mj][ni][jj] * ATT_SCALE + bb[jj];
                s[mj][ni][jj] = (mmj || modd) ? -1e30f : v;
            }
        }
    }

#pragma unroll
    for (int ni = 0; ni < 4; ++ni) {
        float mx = -1e30f;
#pragma unroll
        for (int mj = 0; mj < 4; ++mj)
#pragma unroll
            for (int jj = 0; jj < 4; ++jj) mx = fmaxf(mx, s[mj][ni][jj]);
        mx = fmaxf(mx, __shfl_xor(mx, 16));
        mx = fmaxf(mx, __shfl_xor(mx, 32));
        float sum = 0.f;
#pragma unroll
        for (int mj = 0; mj < 4; ++mj)
#pragma unroll
            for (int jj = 0; jj < 4; ++jj) {
                float p = __expf(s[mj][ni][jj] - mx);
                s[mj][ni][jj] = p;
                sum += p;
            }
        sum += __shfl_xor(sum, 16);
        sum += __shfl_xor(sum, 32);
        float rinv = __builtin_amdgcn_rcpf(sum);
        const int i  = ni * 16 + c;
        const int ik = i & 7;
#pragma unroll
        for (int mj = 0; mj < 4; ++mj) {
            ushort4 pk;
            pk.x = f2bf(s[mj][ni][0] * rinv);
            pk.y = f2bf(s[mj][ni][1] * rinv);
            pk.z = f2bf(s[mj][ni][2] * rinv);
            pk.w = f2bf(s[mj][ni][3] * rinv);
            int chunk = (mj * 2 + (g >> 1)) ^ ik;
            *reinterpret_cast<ushort4*>((char*)&Pl[w][0] + i * 128 + chunk * 16 + (g & 1) * 8) = pk;
        }
    }

    bf16x8 vb[2][2];
#pragma unroll
    for (int nd = 0; nd < 2; ++nd)
#pragma unroll
        for (int kt = 0; kt < 2; ++kt)
            vb[nd][kt] = *reinterpret_cast<const bf16x8*>(
                VT + (size_t)(h * 32 + nd * 16 + c) * 32768 + win * 64 + kt * 32 + g * 8);
    f32x4 o[4][2];
#pragma unroll
    for (int mi = 0; mi < 4; ++mi)
#pragma unroll
        for (int nd = 0; nd < 2; ++nd) { o[mi][nd][0]=0.f; o[mi][nd][1]=0.f; o[mi][nd][2]=0.f; o[mi][nd][3]=0.f; }
#pragma unroll
    for (int mi = 0; mi < 4; ++mi) {
        const int i  = mi * 16 + c;
        const int ik = i & 7;
#pragma unroll
        for (int kt = 0; kt < 2; ++kt) {
            int chunk = (kt * 4 + g) ^ ik;
            bf16x8 pa = *reinterpret_cast<const bf16x8*>((char*)&Pl[w][0] + i * 128 + chunk * 16);
#pragma unroll
            for (int nd = 0; nd < 2; ++nd)
                o[mi][nd] = __builtin_amdgcn_mfma_f32_16x16x32_bf16(pa, vb[nd][kt], o[mi][nd], 0, 0, 0);
        }
    }

    // ---- coalesced AO store via LDS transpose (AOs[64][136] ushorts, 17 KB) ----
    unsigned short* AOs = &Pl[0][0];
    __syncthreads();   // all waves done reading Pl (PV inputs)
#pragma unroll
    for (int mi = 0; mi < 4; ++mi)
#pragma unroll
        for (int nd = 0; nd < 2; ++nd)
#pragma unroll
            for (int jj = 0; jj < 4; ++jj)
                AOs[(mi * 16 + g * 4 + jj) * 136 + w * 32 + nd * 16 + c] = f2bf(o[mi][nd][jj]);
    __syncthreads();
    unsigned short* aop = AO + (size_t)win * 64 * CC + (blockIdx.x & 1) * 128;
    const int u = t & 15, rr2 = t >> 4;
#pragma unroll
    for (int it = 0; it < 4; ++it) {
        int row = it * 16 + rr2;
        uint4 v = *reinterpret_cast<const uint4*>(&AOs[row * 136 + u * 8]);
        *reinterpret_cast<uint4*>(aop + (size_t)row * CC + u * 8) = v;
    }
}

// ---------------- weight cvt + bias expansion, one launch ----------------
__global__ void cvt_bias(const float* s0, const float* s1, const float* s2, const float* s3,
                         const float* s4, const float* s5, const float* s6, const float* s7,
                         const float* s8, const float* s9, unsigned short* __restrict__ dst,
                         const float* __restrict__ sa, const float* __restrict__ ca,
                         float* __restrict__ biasx) {
    int blk = blockIdx.x;
    if (blk >= 1024) {
        int e = (blk - 1024) * 256 + threadIdx.x;        // 0..32767
        const float* src = (e < 16384) ? sa : ca;
        int e2 = e & 16383;
        int h = e2 >> 12, ij = e2 & 4095, i = ij >> 6, j = ij & 63;
        int ri = i >> 3, si = i & 7, rj = j >> 3, sj = j & 7;
        biasx[e] = src[((ri - rj + 7) * 15 + (si - sj + 7)) * 8 + h];
        return;
    }
    const float* srcs[10] = {s0, s1, s2, s3, s4, s5, s6, s7, s8, s9};
    int wi = (blk < 512) ? (blk >> 6) : (blk < 768 ? 8 : 9);
    size_t start = (wi < 8) ? (size_t)wi * 65536 : (wi == 8 ? (size_t)524288 : (size_t)786432);
    size_t gidx = (size_t)blk * 1024 + (size_t)threadIdx.x * 4;
    float4 v = *reinterpret_cast<const float4*>(srcs[wi] + (gidx - start));
    ushort4 o;
    o.x = f2bf(v.x); o.y = f2bf(v.y); o.z = f2bf(v.z); o.w = f2bf(v.w);
    *reinterpret_cast<ushort4*>(dst + gidx) = o;
}

extern "C" void kernel_launch(void* const* d_in, const int* in_sizes, int n_in,
                              void* d_out, int out_size, void* d_ws, size_t ws_size,
                              hipStream_t stream) {
    const float* x    = (const float*)d_in[0];
    const float* ctx  = (const float*)d_in[1];
    const float* ln1w = (const float*)d_in[2];
    const float* ln1b = (const float*)d_in[3];
    const float* ln2w = (const float*)d_in[4];
    const float* ln2b = (const float*)d_in[5];
    const float* ln3w = (const float*)d_in[6];
    const float* ln3b = (const float*)d_in[7];
    const float* lncw = (const float*)d_in[8];
    const float* lncb = (const float*)d_in[9];
    const float* saqw = (const float*)d_in[10];
    const float* saqb = (const float*)d_in[11];
    const float* sakw = (const float*)d_in[12];
    const float* sakb = (const float*)d_in[13];
    const float* savw = (const float*)d_in[14];
    const float* savb = (const float*)d_in[15];
    const float* saow = (const float*)d_in[16];
    const float* saob = (const float*)d_in[17];
    const float* sabias = (const float*)d_in[18];
    const float* caqw = (const float*)d_in[19];
    const float* caqb = (const float*)d_in[20];
    const float* cakw = (const float*)d_in[21];
    const float* cakb = (const float*)d_in[22];
    const float* cavw = (const float*)d_in[23];
    const float* cavb = (const float*)d_in[24];
    const float* caow = (const float*)d_in[25];
    const float* caob = (const float*)d_in[26];
    const float* cabias = (const float*)d_in[27];
    const float* gamma1 = (const float*)d_in[28];
    const float* gamma2 = (const float*)d_in[29];
    const float* gammam = (const float*)d_in[30];
    const float* mw1 = (const float*)d_in[31];
    const float* mb1 = (const float*)d_in[32];
    const float* mw2 = (const float*)d_in[33];
    const float* mb2 = (const float*)d_in[34];

    float* ws = (float*)d_ws;
    unsigned short* LNbf = (unsigned short*)(ws);                 // 3,686,400 f
    unsigned short* Gq   = (unsigned short*)(ws + 3686400);       // 4,194,304 f
    unsigned short* Gkv  = (unsigned short*)(ws + 7880704);       // 4,194,304 f
    unsigned short* Qbf  = (unsigned short*)(ws + 12075008);      // 4,194,304 f
    unsigned short* Kbf  = (unsigned short*)(ws + 16269312);      // 4,194,304 f
    unsigned short* VTbf = (unsigned short*)(ws + 20463616);      // 4,194,304 f
    unsigned short* AObf = (unsigned short*)(ws + 24657920);      // 4,194,304 f
    float* X1  = ws + 28852224;                                   // 7,372,800 f
    unsigned short* Wp = (unsigned short*)(ws + 36225024);        // 524,288 f
    float* biasx = ws + 36749312;                                 // 32,768 f
    unsigned short* H1bf = Qbf;                                   // alias (Q/K/VT/AO dead in MLP phase)

    // cvt layout (contiguous): saq|sak|sav | sao | caq | cak|cav | cao | m1 | m2
    unsigned short* w_saqkv = Wp;                                 // [768][256]
    unsigned short* w_sao   = Wp + 196608;                        // [256][256]
    unsigned short* w_caqkv = Wp + 262144;                        // [768][256] (caq|cak|cav)
    unsigned short* w_cao   = Wp + 458752;                        // [256][256]
    unsigned short* w_m1    = Wp + 524288;                        // [1024][256]
    unsigned short* w_m2    = Wp + 786432;                        // [256][1024]

    float* OUT = (float*)d_out;

    dim3 blk(256);
    dim3 blk512(512);
    dim3 gAttn(WINS * 2);

    cvt_bias<<<dim3(1152), blk, 0, stream>>>(saqw, sakw, savw, saow, caqw, cakw, cavw, caow,
                                             mw1, mw2, Wp, sabias, cabias, biasx);
    // LN1(x) -> Gq (window order) ; LNc(ctx) -> Gkv (window order)
    ln_gather2<<<dim3(16384), blk, 0, stream>>>(x, ln1w, ln1b, Gq, ctx, lncw, lncb, Gkv);

    // ---- self attention ----
    gemm_wa<false,0,256><<<dim3(6, 128), blk512, 0, stream>>>(w_saqkv, Gq, Gq, Gq,
                                                              saqb, sakb, savb, savb,
                                                              Qbf, Kbf, VTbf, VTbf, CC, 2, CC, WROWS,
                                                              nullptr, nullptr, nullptr);
    attn_mfma<<<gAttn, blk, 0, stream>>>(Qbf, Kbf, VTbf, biasx, AObf);
    // sao + residual(x) + LN2 + window re-gather -> Gq (window order)
    gemm_ln<1><<<dim3(256), blk512, 0, stream>>>(w_sao, AObf, saob, x, gamma1, X1, ln2w, ln2b, Gq);

    // ---- cross attention (q from Gq, k/v from Gkv, one launch) ----
    gemm_wa<false,0,256><<<dim3(6, 128), blk512, 0, stream>>>(w_caqkv, Gq, Gkv, Gkv,
                                                              caqb, cakb, cavb, cavb,
                                                              Qbf, Kbf, VTbf, VTbf, CC, 2, CC, WROWS,
                                                              nullptr, nullptr, nullptr);
    attn_mfma<<<gAttn, blk, 0, stream>>>(Qbf, Kbf, VTbf, biasx + 16384, AObf);
    // cao + residual(X1, in place) + LN3 -> LNbf (token order)
    gemm_ln<2><<<dim3(256), blk512, 0, stream>>>(w_cao, AObf, caob, X1, gamma2, X1, ln3w, ln3b, LNbf);

    // ---- MLP ----
    gemm_wa<true,0,256><<<dim3(8, 113), blk512, 0, stream>>>(w_m1, LNbf, LNbf, LNbf,
                                                             mb1, mb1 + 256, mb1 + 512, mb1 + 768,
                                                             H1bf, H1bf + 256, H1bf + 512, H1bf + 768,
                                                             HIDN, -1, CC, BN, nullptr, nullptr, nullptr);
    gemm_wa<false,2,128><<<dim3(2, 225), blk512, 0, stream>>>(w_m2, H1bf, H1bf, H1bf,
                                                             mb2, mb2, mb2, mb2,
                                                             Qbf, Qbf, Qbf, Qbf, CC, -1, HIDN, BN,
                                                             X1, gammam, OUT);
}